// Round 6
// baseline (527.632 us; speedup 1.0000x reference)
//
#include <hip/hip_runtime.h>
#include <cstdint>

typedef unsigned short ushort_t;
typedef __attribute__((ext_vector_type(8))) short short8;
typedef __attribute__((ext_vector_type(4))) short short4_t;
typedef __attribute__((ext_vector_type(4))) float f4;

#define BB   64
#define TT   2048
#define DD   256
#define DO_  128
#define OL   64

// ---- workspace layout (float indices) ----
#define O_TWH   0                 // 131072
#define O_RMAX  131072            // 64
#define O_RDEN  131136            // 64
#define O_CIP   131200            // 262144
#define O_CI    393344            // 16384
#define O_GIC   409728            // 49152
#define O_RIC   458880            // 8192
#define O_S0    467072            // 16384
#define O_SG    483456            // s exchange [2][64 batch][256] = 32768
#define O_LP    516224            // logit partials [2][8 grp][8 bb][128 m][8 q] = 131072
#define O_CTR   647296            // barrier counters 8*64 uint = 512
#define O_RWS   647808            // RWS_g [8 blk][32 kl][128 m] fp32 = 32768
#define O_RWY   680576            // RWY_g [8 blk][16 jl][128 m] fp32 = 16384
#define O_US    696960            // ushort region base (byte 2787840, 16B aligned)
#define U_WB    0                 // 65536: bf16 W_h_a row-major
#define U_BG    65536             // 294912: gate B [blk][n 6][kb 12][lane 64][pos 8]

static __device__ __forceinline__ ushort_t f2bf(float f) {
  union { float f; uint32_t u; } v; v.f = f;
  uint32_t u = v.u;
  u += 0x7FFFu + ((u >> 16) & 1u);   // RNE
  return (ushort_t)(u >> 16);
}
static __device__ __forceinline__ float fast_tanh(float x) {
  float e = __expf(2.f * x);
  return 1.f - 2.f / (e + 1.f);
}
static __device__ __forceinline__ float fast_sigmoid(float x) {
  return 1.f / (1.f + __expf(-x));
}
// LLC-coherent (agent-scope, relaxed) scalar store
static __device__ __forceinline__ void llc_store(float* p, float v) {
  __hip_atomic_store(p, v, __ATOMIC_RELAXED, __HIP_MEMORY_SCOPE_AGENT);
}

// ---------------- K0: weight repack ----------------
__global__ __launch_bounds__(256) void k_prep(const float* __restrict__ Wha,
    const float* __restrict__ Whhg, const float* __restrict__ Wihg,
    const float* __restrict__ Wihr, const float* __restrict__ Whhr,
    float* __restrict__ ws, ushort_t* __restrict__ us) {
  int idx = blockIdx.x * 256 + threadIdx.x;
  if (idx < 65536) {
    us[U_WB + idx] = f2bf(Wha[idx]);
    return;
  }
  if (idx < 65536 + 294912) {
    int i = idx - 65536;
    int pos = i & 7;
    int l = (i >> 3) & 63;
    int r = i >> 9;              // = ((blk*6+n)*12 + kb)
    int kb = r % 12;
    int r2 = r / 12;
    int n = r2 % 6;
    int blk = r2 / 6;
    int c = n * 16 + (l & 15);   // column 0..95
    int g = c >> 5;              // gate 0:r 1:z 2:n
    int kl = c & 31;
    int kg = 32 * blk + kl;      // global k
    int j = kb * 32 + ((l >> 4) & 3) * 8 + pos;   // input index 0..383
    int row = g * 256 + kg;      // gate row
    float v;
    if (j < 256) v = Whhg[row * 256 + j];        // s-input
    else         v = Wihg[row * 384 + j];        // y-input (cols 256..383)
    us[U_BG + i] = f2bf(v);
    return;
  }
  if (idx < 65536 + 294912 + 32768) {
    int i = idx - (65536 + 294912);
    int m = i & 127, kl = (i >> 7) & 31, blk = i >> 12;
    ws[O_RWS + i] = Wihr[m * 512 + 256 + 32 * blk + kl];
  } else {
    int i = idx - (65536 + 294912 + 32768);
    int m = i & 127, jl = (i >> 7) & 15, blk = i >> 11;
    ws[O_RWY + i] = Whhr[m * 128 + 16 * blk + jl];
  }
}

// ---------------- K1: twh[b,t] = sum_h tanh(h.Wha^T) * wa1 (MFMA) ----------------
__global__ __launch_bounds__(256) void k_twh(const float* __restrict__ h,
                                             const ushort_t* __restrict__ Wb,
                                             const float* __restrict__ Wa,
                                             float* __restrict__ twh) {
  __shared__ __align__(16) ushort_t alds[64 * 264];
  __shared__ float walds[256];
  const int tid = threadIdx.x;
  const long rowbase = (long)blockIdx.x * 64;
  walds[tid] = Wa[tid];
  for (int it = 0; it < 8; ++it) {
    int q = it * 256 + tid;
    int r = q >> 5;
    int c8 = q & 31;
    const float* src = h + (rowbase + r) * 256 + c8 * 8;
    float4 a = *(const float4*)(src);
    float4 b = *(const float4*)(src + 4);
    union { ushort_t u[8]; short8 v; } t;
    t.u[0]=f2bf(a.x); t.u[1]=f2bf(a.y); t.u[2]=f2bf(a.z); t.u[3]=f2bf(a.w);
    t.u[4]=f2bf(b.x); t.u[5]=f2bf(b.y); t.u[6]=f2bf(b.z); t.u[7]=f2bf(b.w);
    *(short8*)&alds[r * 264 + c8 * 8] = t.v;
  }
  __syncthreads();
  const int l = tid & 63, w = tid >> 6;
  const int cres = l & 15, kg = l >> 4;
  f4 acc[16];
  #pragma unroll
  for (int f = 0; f < 16; ++f) acc[f] = (f4){0.f, 0.f, 0.f, 0.f};
  const int arow = 16 * w + cres;
  #pragma unroll
  for (int ks = 0; ks < 8; ++ks) {
    short8 af = *(const short8*)&alds[arow * 264 + ks * 32 + kg * 8];
    const ushort_t* bp = Wb + ks * 32 + kg * 8 + cres * 256;
    #pragma unroll
    for (int f = 0; f < 16; ++f) {
      short8 bf = *(const short8*)(bp + f * 16 * 256);
      acc[f] = __builtin_amdgcn_mfma_f32_16x16x32_bf16(af, bf, acc[f], 0, 0, 0);
    }
  }
  float t4[4] = {0.f, 0.f, 0.f, 0.f};
  #pragma unroll
  for (int f = 0; f < 16; ++f) {
    float wa = walds[16 * f + cres];
    #pragma unroll
    for (int r = 0; r < 4; ++r) t4[r] += fast_tanh(acc[f][r]) * wa;
  }
  #pragma unroll
  for (int m = 1; m <= 8; m <<= 1) {
    #pragma unroll
    for (int r = 0; r < 4; ++r) t4[r] += __shfl_xor(t4[r], m);
  }
  if (cres == 0) {
    #pragma unroll
    for (int r = 0; r < 4; ++r)
      twh[rowbase + 16 * w + kg * 4 + r] = t4[r];
  }
}

// ---------------- K2a ----------------
__global__ __launch_bounds__(256) void k_stats(const float* __restrict__ twh,
                                               float* __restrict__ rmax,
                                               float* __restrict__ rden) {
  __shared__ float redm[4], reds[4];
  const int b = blockIdx.x, tid = threadIdx.x;
  float v[8];
  #pragma unroll
  for (int j = 0; j < 8; ++j) v[j] = twh[b * 2048 + tid + j * 256];
  float mx = v[0];
  #pragma unroll
  for (int j = 1; j < 8; ++j) mx = fmaxf(mx, v[j]);
  #pragma unroll
  for (int d = 32; d >= 1; d >>= 1) mx = fmaxf(mx, __shfl_xor(mx, d));
  if ((tid & 63) == 0) redm[tid >> 6] = mx;
  __syncthreads();
  float M = fmaxf(fmaxf(redm[0], redm[1]), fmaxf(redm[2], redm[3]));
  float s = 0.f;
  #pragma unroll
  for (int j = 0; j < 8; ++j) s += __expf(v[j] - M);
  #pragma unroll
  for (int d = 32; d >= 1; d >>= 1) s += __shfl_xor(s, d);
  if ((tid & 63) == 0) reds[tid >> 6] = s;
  __syncthreads();
  if (tid == 0) { rmax[b] = M; rden[b] = reds[0] + reds[1] + reds[2] + reds[3]; }
}

// ---------------- K2b ----------------
__global__ __launch_bounds__(256) void k_cipart(const float* __restrict__ h,
                                                const float* __restrict__ twh,
                                                const float* __restrict__ rmax,
                                                float* __restrict__ cipart) {
  __shared__ float p[128];
  const int b = blockIdx.x >> 4, ts = blockIdx.x & 15;
  const int tid = threadIdx.x;
  const int t0 = ts * 128;
  if (tid < 128) p[tid] = __expf(twh[b * 2048 + t0 + tid] - rmax[b]);
  __syncthreads();
  float acc = 0.f;
  const float* hp = h + ((long)(b * 2048 + t0)) * 256 + tid;
  #pragma unroll 8
  for (int i = 0; i < 128; ++i) { acc += p[i] * hp[0]; hp += 256; }
  cipart[(b * 16 + ts) * 256 + tid] = acc;
}

// ---------------- K2c ----------------
__global__ __launch_bounds__(256) void k_cired(const float* __restrict__ cipart,
                                               const float* __restrict__ rden,
                                               float* __restrict__ ci) {
  const int b = blockIdx.x, d = threadIdx.x;
  float a = 0.f;
  #pragma unroll
  for (int ts = 0; ts < 16; ++ts) a += cipart[(b * 16 + ts) * 256 + d];
  ci[b * 256 + d] = a / rden[b];
}

// ---------------- K3 ----------------
__global__ __launch_bounds__(256) void k_const(const float* __restrict__ h,
    const float* __restrict__ ci,
    const float* __restrict__ Wihg, const float* __restrict__ bihg,
    const float* __restrict__ bhhg,
    const float* __restrict__ Wihr, const float* __restrict__ bihr,
    const float* __restrict__ bhhr,
    const float* __restrict__ Winit, const float* __restrict__ binit,
    float* __restrict__ gic, float* __restrict__ ric, float* __restrict__ s0) {
  __shared__ float cil[256], h0l[256];
  const int b = blockIdx.x, tid = threadIdx.x;
  cil[tid] = ci[b * 256 + tid];
  h0l[tid] = h[(long)b * 2048 * 256 + tid];
  __syncthreads();
  const int k = tid;
  #pragma unroll
  for (int g = 0; g < 3; ++g) {
    float a = bihg[g * 256 + k] + (g < 2 ? bhhg[g * 256 + k] : 0.f);
    const float* wp = Wihg + (long)(g * 256 + k) * 384;
    for (int d = 0; d < 256; d += 4) {
      float4 w4 = *(const float4*)(wp + d);
      a += cil[d] * w4.x + cil[d + 1] * w4.y + cil[d + 2] * w4.z + cil[d + 3] * w4.w;
    }
    gic[b * 768 + g * 256 + k] = a;
  }
  {
    float a = binit[k];
    const float* wp = Winit + (long)k * 256;
    for (int d = 0; d < 256; d += 4) {
      float4 w4 = *(const float4*)(wp + d);
      a += h0l[d] * w4.x + h0l[d + 1] * w4.y + h0l[d + 2] * w4.z + h0l[d + 3] * w4.w;
    }
    s0[b * 256 + k] = fast_tanh(a);
  }
  if (tid < 128) {
    int m = tid;
    float a = bihr[m] + bhhr[m];
    const float* wp = Wihr + (long)m * 512;
    for (int d = 0; d < 256; d += 4) {
      float4 w4 = *(const float4*)(wp + d);
      a += cil[d] * w4.x + cil[d + 1] * w4.y + cil[d + 2] * w4.z + cil[d + 3] * w4.w;
    }
    ric[b * 128 + m] = a;
  }
}

// ---------------- K4: 64-step recurrence, LDS-resident weights ----------------
// 64 blocks = 8 groups x 8 blocks. All cross-block exchange via sc0+sc1
// (LLC-routed) accesses. Reads are batched: ONE inline-asm block issues all
// 5 dwordx4 loads then a single s_waitcnt vmcnt(0) -> one LLC latency
// exposure per step. Barrier: tid0 relaxed add, all waves poll.
__global__ __launch_bounds__(512) void k_loop(
    const float* __restrict__ gic, const float* __restrict__ ric,
    const float* __restrict__ s0w, const float* __restrict__ bhhg,
    const ushort_t* __restrict__ BG, const float* __restrict__ RWSg,
    const float* __restrict__ RWYg,
    float* __restrict__ sg, float* __restrict__ lp,
    unsigned int* __restrict__ ctr,
    float* __restrict__ out) {
  __shared__ __align__(16) ushort_t Bl[36864];   // [n6][kb12][lane64][8] 73728B
  __shared__ __align__(16) ushort_t Al[6144];    // [kb12][kg4][row16][8] 12288B
  __shared__ float RWSl[32][128];
  __shared__ float RWYl[16][128];
  __shared__ float gsum[8][128];                 // r | z | nh | ni
  __shared__ float sslice[8][32];
  __shared__ float ybuf[8][128];
  __shared__ float ricl[8][128];
  __shared__ float gicl[8][3][32];
  __shared__ float bnl[32];
  const int tid = threadIdx.x;
  const int grp = blockIdx.x & 7;
  const int blk = blockIdx.x >> 3;
  const int b0 = grp * 8;

  // ---- one-time LDS fills ----
  {
    const short8* src = (const short8*)(BG + (long)blk * 36864);
    short8* dst = (short8*)Bl;
    for (int i = tid; i < 4608; i += 512) dst[i] = src[i];
  }
  for (int i = tid; i < 4096; i += 512) ((float*)RWSl)[i] = RWSg[blk * 4096 + i];
  for (int i = tid; i < 2048; i += 512) ((float*)RWYl)[i] = RWYg[blk * 2048 + i];
  for (int i = tid; i < 1024; i += 512) ((float*)ricl)[i] = ric[b0 * 128 + i];
  for (int i = tid; i < 768; i += 512) {
    int bb = i / 96, rem = i % 96, g = rem >> 5, kl = rem & 31;
    gicl[bb][g][kl] = gic[(b0 + bb) * 768 + g * 256 + blk * 32 + kl];
  }
  if (tid < 32) bnl[tid] = bhhg[512 + blk * 32 + tid];
  if (tid < 256) {
    int bb = tid >> 5, kl = tid & 31;
    sslice[bb][kl] = s0w[(b0 + bb) * 256 + blk * 32 + kl];
  }
  for (int i = tid; i < 1024; i += 512) ((float*)ybuf)[i] = 0.f;
  // zero A pad rows 8..15 (stay zero forever)
  for (int i = tid; i < 3072; i += 512) {
    int kb = i >> 8, rem = i & 255, kg = rem >> 6, row = 8 + ((rem >> 3) & 7), pos = rem & 7;
    Al[((kb * 4 + kg) * 16 + row) * 8 + pos] = 0;
  }
  __syncthreads();

  for (int it = 0; it <= OL; ++it) {
    const int par = it & 1;
    const int bb1 = tid >> 6, ml = tid & 63;
    f4 sgv;
    // ---- phase 1: batched LLC reads; softmax of prev logits -> y ----
    if (it > 0) {
      const float* a0 = lp + (((long)((par * 8 + grp) * 8 + bb1)) << 10) + ml * 8;
      const float* a1 = a0 + 512;     // ml+64 row
      const float* a2 = sg + par * 16384 + (b0 + bb1) * 256 + ml * 4;
      f4 l0, l1, l2, l3;
      asm volatile(
        "global_load_dwordx4 %0, %5, off sc0 sc1\n\t"
        "global_load_dwordx4 %1, %5, off offset:16 sc0 sc1\n\t"
        "global_load_dwordx4 %2, %6, off sc0 sc1\n\t"
        "global_load_dwordx4 %3, %6, off offset:16 sc0 sc1\n\t"
        "global_load_dwordx4 %4, %7, off sc0 sc1\n\t"
        "s_waitcnt vmcnt(0)"
        : "=&v"(l0), "=&v"(l1), "=&v"(l2), "=&v"(l3), "=&v"(sgv)
        : "v"(a0), "v"(a1), "v"(a2)
        : "memory");
      float L0 = ricl[bb1][ml]      + l0[0]+l0[1]+l0[2]+l0[3] + l1[0]+l1[1]+l1[2]+l1[3];
      float L1 = ricl[bb1][ml + 64] + l2[0]+l2[1]+l2[2]+l2[3] + l3[0]+l3[1]+l3[2]+l3[3];
      L0 = fast_tanh(L0); L1 = fast_tanh(L1);
      float e0 = __expf(L0), e1 = __expf(L1);
      float s = e0 + e1;
      #pragma unroll
      for (int d = 32; d >= 1; d >>= 1) s += __shfl_xor(s, d);
      float y0 = e0 / s, y1 = e1 / s;
      ybuf[bb1][ml] = y0; ybuf[bb1][ml + 64] = y1;
      if (bb1 == blk) {
        float* op = out + ((long)(b0 + blk) * OL + (it - 1)) * DO_;
        op[ml] = y0; op[ml + 64] = y1;
      }
    } else {
      sgv = *(const f4*)(s0w + (b0 + bb1) * 256 + ml * 4);
    }
    if (it == OL) break;
    __syncthreads();
    // ---- phase 3: build A (bf16) rows=batch, cols 0..255=s, 256..383=y ----
    {
      const int j4 = ml * 4;
      int kb = j4 >> 5, kg = (j4 >> 3) & 3, pos = j4 & 7;
      short4_t h4;
      h4[0] = (short)f2bf(sgv[0]); h4[1] = (short)f2bf(sgv[1]);
      h4[2] = (short)f2bf(sgv[2]); h4[3] = (short)f2bf(sgv[3]);
      *(short4_t*)&Al[((kb * 4 + kg) * 16 + bb1) * 8 + pos] = h4;
    }
    if (tid < 256) {
      const int bb = tid >> 5, jl4 = (tid & 31) * 4;
      const int j = 256 + jl4;
      int kb = j >> 5, kg = (j >> 3) & 3, pos = j & 7;
      short4_t h4;
      h4[0] = (short)f2bf(ybuf[bb][jl4]);     h4[1] = (short)f2bf(ybuf[bb][jl4 + 1]);
      h4[2] = (short)f2bf(ybuf[bb][jl4 + 2]); h4[3] = (short)f2bf(ybuf[bb][jl4 + 3]);
      *(short4_t*)&Al[((kb * 4 + kg) * 16 + bb) * 8 + pos] = h4;
    }
    __syncthreads();
    // ---- phase 5: gate MFMA (waves 0,1), K-split stash separates nh/ni ----
    if (tid < 128) {
      const int w = tid >> 6, l = tid & 63;
      f4 a0 = (f4){0,0,0,0}, a1 = (f4){0,0,0,0}, a2 = (f4){0,0,0,0};
      f4 m1 = (f4){0,0,0,0}, m2 = (f4){0,0,0,0};
      const short8* Ap = (const short8*)Al + l;
      const short8* Bp = (const short8*)Bl + (w * 3) * 768 + l;
      #pragma unroll
      for (int kb = 0; kb < 12; ++kb) {
        short8 af = Ap[kb * 64];
        a0 = __builtin_amdgcn_mfma_f32_16x16x32_bf16(af, Bp[kb * 64], a0, 0, 0, 0);
        a1 = __builtin_amdgcn_mfma_f32_16x16x32_bf16(af, Bp[768 + kb * 64], a1, 0, 0, 0);
        a2 = __builtin_amdgcn_mfma_f32_16x16x32_bf16(af, Bp[1536 + kb * 64], a2, 0, 0, 0);
        if (kb == 7) { m1 = a1; m2 = a2; }   // s-part only (used by wave 1)
      }
      if (l < 32) {
        const int bbase = (l >> 4) * 4, c = l & 15;
        if (w == 0) {
          #pragma unroll
          for (int r = 0; r < 4; ++r) {
            gsum[bbase + r][c]      = a0[r];
            gsum[bbase + r][16 + c] = a1[r];
            gsum[bbase + r][32 + c] = a2[r];
          }
        } else {
          #pragma unroll
          for (int r = 0; r < 4; ++r) {
            gsum[bbase + r][48 + c] = a0[r];          // z hi
            gsum[bbase + r][64 + c]      = m1[r];     // nh lo  (s-part)
            gsum[bbase + r][96 + c]      = a1[r] - m1[r]; // ni lo (y-part)
            gsum[bbase + r][64 + 16 + c] = m2[r];     // nh hi
            gsum[bbase + r][96 + 16 + c] = a2[r] - m2[r]; // ni hi
          }
        }
      }
    }
    __syncthreads();
    // ---- phase 7: GRU update for k-slice ----
    if (tid < 256) {
      const int bb = tid >> 5, kl = tid & 31;
      float sold = sslice[bb][kl];
      float R   = fast_sigmoid(gsum[bb][kl]      + gicl[bb][0][kl]);
      float Z   = fast_sigmoid(gsum[bb][32 + kl] + gicl[bb][1][kl]);
      float hn  = gsum[bb][64 + kl] + bnl[kl];
      float in_ = gsum[bb][96 + kl] + gicl[bb][2][kl];
      float N = fast_tanh(in_ + R * hn);
      float sn = (1.f - Z) * N + Z * sold;
      sslice[bb][kl] = sn;
      llc_store(sg + (par ^ 1) * 16384 + (b0 + bb) * 256 + blk * 32 + kl, sn);
    }
    __syncthreads();
    // ---- phase 9: RNN logit partials (own k-slice + own jy-slice) ----
    {
      const int m = tid & 127, q = tid >> 7;
      const int ba = 2 * q, bbv = 2 * q + 1;
      float acc0 = 0.f, acc1 = 0.f;
      #pragma unroll 8
      for (int kl = 0; kl < 32; ++kl) {
        float w = RWSl[kl][m];
        acc0 += w * sslice[ba][kl];
        acc1 += w * sslice[bbv][kl];
      }
      #pragma unroll 8
      for (int jl = 0; jl < 16; ++jl) {
        float w = RWYl[jl][m];
        acc0 += w * ybuf[ba][16 * blk + jl];
        acc1 += w * ybuf[bbv][16 * blk + jl];
      }
      // layout [par][grp][bb][m][q]
      float* dst = lp + (((long)((par ^ 1) * 8 + grp) * 8) << 10);
      llc_store(dst + (ba  << 10) + m * 8 + blk, acc0);
      llc_store(dst + (bbv << 10) + m * 8 + blk, acc1);
    }
    // ---- group barrier (one per step) ----
    __syncthreads();   // drains vmcnt per wave => sc1 stores at LLC
    unsigned int* c = ctr + grp * 64 + it;
    if (tid == 0)
      __hip_atomic_fetch_add(c, 1u, __ATOMIC_RELAXED, __HIP_MEMORY_SCOPE_AGENT);
    while (__hip_atomic_load(c, __ATOMIC_RELAXED, __HIP_MEMORY_SCOPE_AGENT) < 8u)
      __builtin_amdgcn_s_sleep(1);
  }
}

extern "C" void kernel_launch(void* const* d_in, const int* in_sizes, int n_in,
                              void* d_out, int out_size, void* d_ws, size_t ws_size,
                              hipStream_t stream) {
  const float* h     = (const float*)d_in[0];
  const float* Wha   = (const float*)d_in[1];
  const float* Wa    = (const float*)d_in[4];
  const float* Winit = (const float*)d_in[5];
  const float* binit = (const float*)d_in[6];
  const float* Wihg  = (const float*)d_in[7];
  const float* Whhg  = (const float*)d_in[8];
  const float* bihg  = (const float*)d_in[9];
  const float* bhhg  = (const float*)d_in[10];
  const float* Wihr  = (const float*)d_in[11];
  const float* Whhr  = (const float*)d_in[12];
  const float* bihr  = (const float*)d_in[13];
  const float* bhhr  = (const float*)d_in[14];
  float* ws  = (float*)d_ws;
  float* out = (float*)d_out;
  ushort_t* us = (ushort_t*)(ws + O_US);

  // zero the barrier counters (capturable memset node, stream-ordered)
  hipMemsetAsync((char*)d_ws + (size_t)O_CTR * 4, 0, 512 * 4, stream);

  k_prep<<<dim3(1600), dim3(256), 0, stream>>>(Wha, Whhg, Wihg, Wihr, Whhr, ws, us);
  k_twh<<<dim3(2048), dim3(256), 0, stream>>>(h, us + U_WB, Wa, ws + O_TWH);
  k_stats<<<dim3(64), dim3(256), 0, stream>>>(ws + O_TWH, ws + O_RMAX, ws + O_RDEN);
  k_cipart<<<dim3(1024), dim3(256), 0, stream>>>(h, ws + O_TWH, ws + O_RMAX, ws + O_CIP);
  k_cired<<<dim3(64), dim3(256), 0, stream>>>(ws + O_CIP, ws + O_RDEN, ws + O_CI);
  k_const<<<dim3(64), dim3(256), 0, stream>>>(h, ws + O_CI, Wihg, bihg, bhhg,
                                              Wihr, bihr, bhhr, Winit, binit,
                                              ws + O_GIC, ws + O_RIC, ws + O_S0);
  k_loop<<<dim3(64), dim3(512), 0, stream>>>(ws + O_GIC, ws + O_RIC, ws + O_S0, bhhg,
                                             us + U_BG, ws + O_RWS, ws + O_RWY,
                                             ws + O_SG, ws + O_LP,
                                             (unsigned int*)(ws + O_CTR),
                                             out);
}

// Round 7
// 472.718 us; speedup vs baseline: 1.1162x; 1.1162x over previous
//
#include <hip/hip_runtime.h>
#include <cstdint>

typedef unsigned short ushort_t;
typedef __attribute__((ext_vector_type(8))) short short8;
typedef __attribute__((ext_vector_type(4))) short short4_t;
typedef __attribute__((ext_vector_type(4))) float f4;

#define BB   64
#define TT   2048
#define DD   256
#define DO_  128
#define OL   64

// ---- workspace layout (float indices) ----
#define O_TWH   0                 // 131072
#define O_RMAX  131072            // 64
#define O_RDEN  131136            // 64
#define O_CIP   131200            // 262144
#define O_CI    393344            // 16384
#define O_GIC   409728            // 49152
#define O_RIC   458880            // 8192
#define O_S0    467072            // 16384
#define O_SG    483456            // s exchange [2][64 batch][256] = 32768
#define O_LP    516224            // logit partials [2][8 grp][8 bb][8 q][128 m] = 131072
#define O_CTR   647296            // barrier counters 8*64 uint = 512
#define O_RWS   647808            // RWS_g [8 blk][32 kl][128 m] fp32 = 32768
#define O_RWY   680576            // RWY_g [8 blk][16 jl][128 m] fp32 = 16384
#define O_US    696960            // ushort region base (byte 2787840, 16B aligned)
#define U_WB    0                 // 65536: bf16 W_h_a row-major
#define U_BG    65536             // 294912: gate B [blk][n 6][kb 12][lane 64][pos 8]

static __device__ __forceinline__ ushort_t f2bf(float f) {
  union { float f; uint32_t u; } v; v.f = f;
  uint32_t u = v.u;
  u += 0x7FFFu + ((u >> 16) & 1u);   // RNE
  return (ushort_t)(u >> 16);
}
static __device__ __forceinline__ float fast_tanh(float x) {
  float e = __expf(2.f * x);
  return 1.f - 2.f / (e + 1.f);
}
static __device__ __forceinline__ float fast_sigmoid(float x) {
  return 1.f / (1.f + __expf(-x));
}
// LLC-coherent (agent-scope, relaxed) scalar store
static __device__ __forceinline__ void llc_store(float* p, float v) {
  __hip_atomic_store(p, v, __ATOMIC_RELAXED, __HIP_MEMORY_SCOPE_AGENT);
}

// ---------------- K0: weight repack ----------------
__global__ __launch_bounds__(256) void k_prep(const float* __restrict__ Wha,
    const float* __restrict__ Whhg, const float* __restrict__ Wihg,
    const float* __restrict__ Wihr, const float* __restrict__ Whhr,
    float* __restrict__ ws, ushort_t* __restrict__ us) {
  int idx = blockIdx.x * 256 + threadIdx.x;
  if (idx < 65536) {
    us[U_WB + idx] = f2bf(Wha[idx]);
    return;
  }
  if (idx < 65536 + 294912) {
    int i = idx - 65536;
    int pos = i & 7;
    int l = (i >> 3) & 63;
    int r = i >> 9;              // = ((blk*6+n)*12 + kb)
    int kb = r % 12;
    int r2 = r / 12;
    int n = r2 % 6;
    int blk = r2 / 6;
    int c = n * 16 + (l & 15);   // column 0..95
    int g = c >> 5;              // gate 0:r 1:z 2:n
    int kl = c & 31;
    int kg = 32 * blk + kl;      // global k
    int j = kb * 32 + ((l >> 4) & 3) * 8 + pos;   // input index 0..383
    int row = g * 256 + kg;      // gate row
    float v;
    if (j < 256) v = Whhg[row * 256 + j];        // s-input
    else         v = Wihg[row * 384 + j];        // y-input (cols 256..383)
    us[U_BG + i] = f2bf(v);
    return;
  }
  if (idx < 65536 + 294912 + 32768) {
    int i = idx - (65536 + 294912);
    int m = i & 127, kl = (i >> 7) & 31, blk = i >> 12;
    ws[O_RWS + i] = Wihr[m * 512 + 256 + 32 * blk + kl];
  } else {
    int i = idx - (65536 + 294912 + 32768);
    int m = i & 127, jl = (i >> 7) & 15, blk = i >> 11;
    ws[O_RWY + i] = Whhr[m * 128 + 16 * blk + jl];
  }
}

// ---------------- K1: twh[b,t] = sum_h tanh(h.Wha^T) * wa1 (MFMA) ----------------
__global__ __launch_bounds__(256) void k_twh(const float* __restrict__ h,
                                             const ushort_t* __restrict__ Wb,
                                             const float* __restrict__ Wa,
                                             float* __restrict__ twh) {
  __shared__ __align__(16) ushort_t alds[64 * 264];
  __shared__ float walds[256];
  const int tid = threadIdx.x;
  const long rowbase = (long)blockIdx.x * 64;
  walds[tid] = Wa[tid];
  for (int it = 0; it < 8; ++it) {
    int q = it * 256 + tid;
    int r = q >> 5;
    int c8 = q & 31;
    const float* src = h + (rowbase + r) * 256 + c8 * 8;
    float4 a = *(const float4*)(src);
    float4 b = *(const float4*)(src + 4);
    union { ushort_t u[8]; short8 v; } t;
    t.u[0]=f2bf(a.x); t.u[1]=f2bf(a.y); t.u[2]=f2bf(a.z); t.u[3]=f2bf(a.w);
    t.u[4]=f2bf(b.x); t.u[5]=f2bf(b.y); t.u[6]=f2bf(b.z); t.u[7]=f2bf(b.w);
    *(short8*)&alds[r * 264 + c8 * 8] = t.v;
  }
  __syncthreads();
  const int l = tid & 63, w = tid >> 6;
  const int cres = l & 15, kg = l >> 4;
  f4 acc[16];
  #pragma unroll
  for (int f = 0; f < 16; ++f) acc[f] = (f4){0.f, 0.f, 0.f, 0.f};
  const int arow = 16 * w + cres;
  #pragma unroll
  for (int ks = 0; ks < 8; ++ks) {
    short8 af = *(const short8*)&alds[arow * 264 + ks * 32 + kg * 8];
    const ushort_t* bp = Wb + ks * 32 + kg * 8 + cres * 256;
    #pragma unroll
    for (int f = 0; f < 16; ++f) {
      short8 bf = *(const short8*)(bp + f * 16 * 256);
      acc[f] = __builtin_amdgcn_mfma_f32_16x16x32_bf16(af, bf, acc[f], 0, 0, 0);
    }
  }
  float t4[4] = {0.f, 0.f, 0.f, 0.f};
  #pragma unroll
  for (int f = 0; f < 16; ++f) {
    float wa = walds[16 * f + cres];
    #pragma unroll
    for (int r = 0; r < 4; ++r) t4[r] += fast_tanh(acc[f][r]) * wa;
  }
  #pragma unroll
  for (int m = 1; m <= 8; m <<= 1) {
    #pragma unroll
    for (int r = 0; r < 4; ++r) t4[r] += __shfl_xor(t4[r], m);
  }
  if (cres == 0) {
    #pragma unroll
    for (int r = 0; r < 4; ++r)
      twh[rowbase + 16 * w + kg * 4 + r] = t4[r];
  }
}

// ---------------- K2a ----------------
__global__ __launch_bounds__(256) void k_stats(const float* __restrict__ twh,
                                               float* __restrict__ rmax,
                                               float* __restrict__ rden) {
  __shared__ float redm[4], reds[4];
  const int b = blockIdx.x, tid = threadIdx.x;
  float v[8];
  #pragma unroll
  for (int j = 0; j < 8; ++j) v[j] = twh[b * 2048 + tid + j * 256];
  float mx = v[0];
  #pragma unroll
  for (int j = 1; j < 8; ++j) mx = fmaxf(mx, v[j]);
  #pragma unroll
  for (int d = 32; d >= 1; d >>= 1) mx = fmaxf(mx, __shfl_xor(mx, d));
  if ((tid & 63) == 0) redm[tid >> 6] = mx;
  __syncthreads();
  float M = fmaxf(fmaxf(redm[0], redm[1]), fmaxf(redm[2], redm[3]));
  float s = 0.f;
  #pragma unroll
  for (int j = 0; j < 8; ++j) s += __expf(v[j] - M);
  #pragma unroll
  for (int d = 32; d >= 1; d >>= 1) s += __shfl_xor(s, d);
  if ((tid & 63) == 0) reds[tid >> 6] = s;
  __syncthreads();
  if (tid == 0) { rmax[b] = M; rden[b] = reds[0] + reds[1] + reds[2] + reds[3]; }
}

// ---------------- K2b ----------------
__global__ __launch_bounds__(256) void k_cipart(const float* __restrict__ h,
                                                const float* __restrict__ twh,
                                                const float* __restrict__ rmax,
                                                float* __restrict__ cipart) {
  __shared__ float p[128];
  const int b = blockIdx.x >> 4, ts = blockIdx.x & 15;
  const int tid = threadIdx.x;
  const int t0 = ts * 128;
  if (tid < 128) p[tid] = __expf(twh[b * 2048 + t0 + tid] - rmax[b]);
  __syncthreads();
  float acc = 0.f;
  const float* hp = h + ((long)(b * 2048 + t0)) * 256 + tid;
  #pragma unroll 8
  for (int i = 0; i < 128; ++i) { acc += p[i] * hp[0]; hp += 256; }
  cipart[(b * 16 + ts) * 256 + tid] = acc;
}

// ---------------- K2c ----------------
__global__ __launch_bounds__(256) void k_cired(const float* __restrict__ cipart,
                                               const float* __restrict__ rden,
                                               float* __restrict__ ci) {
  const int b = blockIdx.x, d = threadIdx.x;
  float a = 0.f;
  #pragma unroll
  for (int ts = 0; ts < 16; ++ts) a += cipart[(b * 16 + ts) * 256 + d];
  ci[b * 256 + d] = a / rden[b];
}

// ---------------- K3 ----------------
__global__ __launch_bounds__(256) void k_const(const float* __restrict__ h,
    const float* __restrict__ ci,
    const float* __restrict__ Wihg, const float* __restrict__ bihg,
    const float* __restrict__ bhhg,
    const float* __restrict__ Wihr, const float* __restrict__ bihr,
    const float* __restrict__ bhhr,
    const float* __restrict__ Winit, const float* __restrict__ binit,
    float* __restrict__ gic, float* __restrict__ ric, float* __restrict__ s0) {
  __shared__ float cil[256], h0l[256];
  const int b = blockIdx.x, tid = threadIdx.x;
  cil[tid] = ci[b * 256 + tid];
  h0l[tid] = h[(long)b * 2048 * 256 + tid];
  __syncthreads();
  const int k = tid;
  #pragma unroll
  for (int g = 0; g < 3; ++g) {
    float a = bihg[g * 256 + k] + (g < 2 ? bhhg[g * 256 + k] : 0.f);
    const float* wp = Wihg + (long)(g * 256 + k) * 384;
    for (int d = 0; d < 256; d += 4) {
      float4 w4 = *(const float4*)(wp + d);
      a += cil[d] * w4.x + cil[d + 1] * w4.y + cil[d + 2] * w4.z + cil[d + 3] * w4.w;
    }
    gic[b * 768 + g * 256 + k] = a;
  }
  {
    float a = binit[k];
    const float* wp = Winit + (long)k * 256;
    for (int d = 0; d < 256; d += 4) {
      float4 w4 = *(const float4*)(wp + d);
      a += h0l[d] * w4.x + h0l[d + 1] * w4.y + h0l[d + 2] * w4.z + h0l[d + 3] * w4.w;
    }
    s0[b * 256 + k] = fast_tanh(a);
  }
  if (tid < 128) {
    int m = tid;
    float a = bihr[m] + bhhr[m];
    const float* wp = Wihr + (long)m * 512;
    for (int d = 0; d < 256; d += 4) {
      float4 w4 = *(const float4*)(wp + d);
      a += cil[d] * w4.x + cil[d + 1] * w4.y + cil[d + 2] * w4.z + cil[d + 3] * w4.w;
    }
    ric[b * 128 + m] = a;
  }
}

// ---------------- K4: 64-step recurrence, LDS-resident weights ----------------
// 64 blocks = 8 groups x 8 blocks. Cross-block exchange via sc0+sc1 LLC ops.
// lp layout [par][grp][bb][q][m]: writer q=blk stores 128-float contiguous
// chunks (coalesced, no write amplification); reader finds all 16 partials
// within a 3840B window of ONE base address -> one asm block, 17 loads,
// single s_waitcnt vmcnt(0) (one LLC latency exposure per step).
__global__ __launch_bounds__(512) void k_loop(
    const float* __restrict__ gic, const float* __restrict__ ric,
    const float* __restrict__ s0w, const float* __restrict__ bhhg,
    const ushort_t* __restrict__ BG, const float* __restrict__ RWSg,
    const float* __restrict__ RWYg,
    float* __restrict__ sg, float* __restrict__ lp,
    unsigned int* __restrict__ ctr,
    float* __restrict__ out) {
  __shared__ __align__(16) ushort_t Bl[36864];   // [n6][kb12][lane64][8] 73728B
  __shared__ __align__(16) ushort_t Al[6144];    // [kb12][kg4][row16][8] 12288B
  __shared__ float RWSl[32][128];
  __shared__ float RWYl[16][128];
  __shared__ float gsum[8][128];                 // r | z | nh | ni
  __shared__ float sslice[8][32];
  __shared__ float ybuf[8][128];
  __shared__ float ricl[8][128];
  __shared__ float gicl[8][3][32];
  __shared__ float bnl[32];
  const int tid = threadIdx.x;
  const int grp = blockIdx.x & 7;
  const int blk = blockIdx.x >> 3;
  const int b0 = grp * 8;

  // ---- one-time LDS fills ----
  {
    const short8* src = (const short8*)(BG + (long)blk * 36864);
    short8* dst = (short8*)Bl;
    for (int i = tid; i < 4608; i += 512) dst[i] = src[i];
  }
  for (int i = tid; i < 4096; i += 512) ((float*)RWSl)[i] = RWSg[blk * 4096 + i];
  for (int i = tid; i < 2048; i += 512) ((float*)RWYl)[i] = RWYg[blk * 2048 + i];
  for (int i = tid; i < 1024; i += 512) ((float*)ricl)[i] = ric[b0 * 128 + i];
  for (int i = tid; i < 768; i += 512) {
    int bb = i / 96, rem = i % 96, g = rem >> 5, kl = rem & 31;
    gicl[bb][g][kl] = gic[(b0 + bb) * 768 + g * 256 + blk * 32 + kl];
  }
  if (tid < 32) bnl[tid] = bhhg[512 + blk * 32 + tid];
  if (tid < 256) {
    int bb = tid >> 5, kl = tid & 31;
    sslice[bb][kl] = s0w[(b0 + bb) * 256 + blk * 32 + kl];
  }
  for (int i = tid; i < 1024; i += 512) ((float*)ybuf)[i] = 0.f;
  // zero A pad rows 8..15 (stay zero forever)
  for (int i = tid; i < 3072; i += 512) {
    int kb = i >> 8, rem = i & 255, kg = rem >> 6, row = 8 + ((rem >> 3) & 7), pos = rem & 7;
    Al[((kb * 4 + kg) * 16 + row) * 8 + pos] = 0;
  }
  __syncthreads();

  for (int it = 0; it <= OL; ++it) {
    const int par = it & 1;
    const int bb1 = tid >> 6, ml = tid & 63;
    f4 sgv;
    // ---- phase 1: batched LLC reads; softmax of prev logits -> y ----
    if (it > 0) {
      const float* aL = lp + (((long)((par * 8 + grp) * 8 + bb1)) << 10) + ml;
      const float* a2 = sg + par * 16384 + (b0 + bb1) * 256 + ml * 4;
      float r0,r1,r2,r3,r4,r5,r6,r7,r8,r9,r10,r11,r12,r13,r14,r15;
      asm volatile(
        "global_load_dword %0, %17, off sc0 sc1\n\t"
        "global_load_dword %1, %17, off offset:512 sc0 sc1\n\t"
        "global_load_dword %2, %17, off offset:1024 sc0 sc1\n\t"
        "global_load_dword %3, %17, off offset:1536 sc0 sc1\n\t"
        "global_load_dword %4, %17, off offset:2048 sc0 sc1\n\t"
        "global_load_dword %5, %17, off offset:2560 sc0 sc1\n\t"
        "global_load_dword %6, %17, off offset:3072 sc0 sc1\n\t"
        "global_load_dword %7, %17, off offset:3584 sc0 sc1\n\t"
        "global_load_dword %8, %17, off offset:256 sc0 sc1\n\t"
        "global_load_dword %9, %17, off offset:768 sc0 sc1\n\t"
        "global_load_dword %10, %17, off offset:1280 sc0 sc1\n\t"
        "global_load_dword %11, %17, off offset:1792 sc0 sc1\n\t"
        "global_load_dword %12, %17, off offset:2304 sc0 sc1\n\t"
        "global_load_dword %13, %17, off offset:2816 sc0 sc1\n\t"
        "global_load_dword %14, %17, off offset:3328 sc0 sc1\n\t"
        "global_load_dword %15, %17, off offset:3840 sc0 sc1\n\t"
        "global_load_dwordx4 %16, %18, off sc0 sc1\n\t"
        "s_waitcnt vmcnt(0)"
        : "=&v"(r0), "=&v"(r1), "=&v"(r2), "=&v"(r3),
          "=&v"(r4), "=&v"(r5), "=&v"(r6), "=&v"(r7),
          "=&v"(r8), "=&v"(r9), "=&v"(r10), "=&v"(r11),
          "=&v"(r12), "=&v"(r13), "=&v"(r14), "=&v"(r15),
          "=&v"(sgv)
        : "v"(aL), "v"(a2)
        : "memory");
      float L0 = ricl[bb1][ml]      + ((r0+r1)+(r2+r3)) + ((r4+r5)+(r6+r7));
      float L1 = ricl[bb1][ml + 64] + ((r8+r9)+(r10+r11)) + ((r12+r13)+(r14+r15));
      L0 = fast_tanh(L0); L1 = fast_tanh(L1);
      float e0 = __expf(L0), e1 = __expf(L1);
      float s = e0 + e1;
      #pragma unroll
      for (int d = 32; d >= 1; d >>= 1) s += __shfl_xor(s, d);
      float y0 = e0 / s, y1 = e1 / s;
      ybuf[bb1][ml] = y0; ybuf[bb1][ml + 64] = y1;
      if (bb1 == blk) {
        float* op = out + ((long)(b0 + blk) * OL + (it - 1)) * DO_;
        op[ml] = y0; op[ml + 64] = y1;
      }
    } else {
      sgv = *(const f4*)(s0w + (b0 + bb1) * 256 + ml * 4);
    }
    if (it == OL) break;
    __syncthreads();
    // ---- phase 3: build A (bf16) rows=batch, cols 0..255=s, 256..383=y ----
    {
      const int j4 = ml * 4;
      int kb = j4 >> 5, kg = (j4 >> 3) & 3, pos = j4 & 7;
      short4_t h4;
      h4[0] = (short)f2bf(sgv[0]); h4[1] = (short)f2bf(sgv[1]);
      h4[2] = (short)f2bf(sgv[2]); h4[3] = (short)f2bf(sgv[3]);
      *(short4_t*)&Al[((kb * 4 + kg) * 16 + bb1) * 8 + pos] = h4;
    }
    if (tid < 256) {
      const int bb = tid >> 5, jl4 = (tid & 31) * 4;
      const int j = 256 + jl4;
      int kb = j >> 5, kg = (j >> 3) & 3, pos = j & 7;
      short4_t h4;
      h4[0] = (short)f2bf(ybuf[bb][jl4]);     h4[1] = (short)f2bf(ybuf[bb][jl4 + 1]);
      h4[2] = (short)f2bf(ybuf[bb][jl4 + 2]); h4[3] = (short)f2bf(ybuf[bb][jl4 + 3]);
      *(short4_t*)&Al[((kb * 4 + kg) * 16 + bb) * 8 + pos] = h4;
    }
    __syncthreads();
    // ---- phase 5: gate MFMA (waves 0,1), K-split stash separates nh/ni ----
    if (tid < 128) {
      const int w = tid >> 6, l = tid & 63;
      f4 a0 = (f4){0,0,0,0}, a1 = (f4){0,0,0,0}, a2v = (f4){0,0,0,0};
      f4 m1 = (f4){0,0,0,0}, m2 = (f4){0,0,0,0};
      const short8* Ap = (const short8*)Al + l;
      const short8* Bp = (const short8*)Bl + (w * 3) * 768 + l;
      #pragma unroll
      for (int kb = 0; kb < 12; ++kb) {
        short8 af = Ap[kb * 64];
        a0 = __builtin_amdgcn_mfma_f32_16x16x32_bf16(af, Bp[kb * 64], a0, 0, 0, 0);
        a1 = __builtin_amdgcn_mfma_f32_16x16x32_bf16(af, Bp[768 + kb * 64], a1, 0, 0, 0);
        a2v = __builtin_amdgcn_mfma_f32_16x16x32_bf16(af, Bp[1536 + kb * 64], a2v, 0, 0, 0);
        if (kb == 7) { m1 = a1; m2 = a2v; }   // s-part only (used by wave 1)
      }
      if (l < 32) {
        const int bbase = (l >> 4) * 4, c = l & 15;
        if (w == 0) {
          #pragma unroll
          for (int r = 0; r < 4; ++r) {
            gsum[bbase + r][c]      = a0[r];
            gsum[bbase + r][16 + c] = a1[r];
            gsum[bbase + r][32 + c] = a2v[r];
          }
        } else {
          #pragma unroll
          for (int r = 0; r < 4; ++r) {
            gsum[bbase + r][48 + c] = a0[r];          // z hi
            gsum[bbase + r][64 + c]      = m1[r];     // nh lo  (s-part)
            gsum[bbase + r][96 + c]      = a1[r] - m1[r]; // ni lo (y-part)
            gsum[bbase + r][64 + 16 + c] = m2[r];     // nh hi
            gsum[bbase + r][96 + 16 + c] = a2v[r] - m2[r]; // ni hi
          }
        }
      }
    }
    __syncthreads();
    // ---- phase 7: GRU update for k-slice ----
    if (tid < 256) {
      const int bb = tid >> 5, kl = tid & 31;
      float sold = sslice[bb][kl];
      float R   = fast_sigmoid(gsum[bb][kl]      + gicl[bb][0][kl]);
      float Z   = fast_sigmoid(gsum[bb][32 + kl] + gicl[bb][1][kl]);
      float hn  = gsum[bb][64 + kl] + bnl[kl];
      float in_ = gsum[bb][96 + kl] + gicl[bb][2][kl];
      float N = fast_tanh(in_ + R * hn);
      float sn = (1.f - Z) * N + Z * sold;
      sslice[bb][kl] = sn;
      llc_store(sg + (par ^ 1) * 16384 + (b0 + bb) * 256 + blk * 32 + kl, sn);
    }
    __syncthreads();
    // ---- phase 9: RNN logit partials (own k-slice + own jy-slice) ----
    {
      const int m = tid & 127, q = tid >> 7;
      const int ba = 2 * q, bbv = 2 * q + 1;
      float acc0 = 0.f, acc1 = 0.f;
      #pragma unroll 8
      for (int kl = 0; kl < 32; ++kl) {
        float w = RWSl[kl][m];
        acc0 += w * sslice[ba][kl];
        acc1 += w * sslice[bbv][kl];
      }
      #pragma unroll 8
      for (int jl = 0; jl < 16; ++jl) {
        float w = RWYl[jl][m];
        acc0 += w * ybuf[ba][16 * blk + jl];
        acc1 += w * ybuf[bbv][16 * blk + jl];
      }
      // layout [par][grp][bb][q][m]: q=blk chunk of 128 floats (coalesced)
      float* dst = lp + (((long)((par ^ 1) * 8 + grp) * 8) << 10) + blk * 128 + m;
      llc_store(dst + (ba  << 10), acc0);
      llc_store(dst + (bbv << 10), acc1);
    }
    // ---- group barrier (one per step) ----
    __syncthreads();   // drains vmcnt per wave => sc1 stores at LLC
    if (tid == 0) {
      unsigned int* c = ctr + grp * 64 + it;
      __hip_atomic_fetch_add(c, 1u, __ATOMIC_RELAXED, __HIP_MEMORY_SCOPE_AGENT);
      while (__hip_atomic_load(c, __ATOMIC_RELAXED, __HIP_MEMORY_SCOPE_AGENT) < 8u) {
        __builtin_amdgcn_s_sleep(2);
      }
    }
    __syncthreads();
  }
}

extern "C" void kernel_launch(void* const* d_in, const int* in_sizes, int n_in,
                              void* d_out, int out_size, void* d_ws, size_t ws_size,
                              hipStream_t stream) {
  const float* h     = (const float*)d_in[0];
  const float* Wha   = (const float*)d_in[1];
  const float* Wa    = (const float*)d_in[4];
  const float* Winit = (const float*)d_in[5];
  const float* binit = (const float*)d_in[6];
  const float* Wihg  = (const float*)d_in[7];
  const float* Whhg  = (const float*)d_in[8];
  const float* bihg  = (const float*)d_in[9];
  const float* bhhg  = (const float*)d_in[10];
  const float* Wihr  = (const float*)d_in[11];
  const float* Whhr  = (const float*)d_in[12];
  const float* bihr  = (const float*)d_in[13];
  const float* bhhr  = (const float*)d_in[14];
  float* ws  = (float*)d_ws;
  float* out = (float*)d_out;
  ushort_t* us = (ushort_t*)(ws + O_US);

  // zero the barrier counters (capturable memset node, stream-ordered)
  hipMemsetAsync((char*)d_ws + (size_t)O_CTR * 4, 0, 512 * 4, stream);

  k_prep<<<dim3(1600), dim3(256), 0, stream>>>(Wha, Whhg, Wihg, Wihr, Whhr, ws, us);
  k_twh<<<dim3(2048), dim3(256), 0, stream>>>(h, us + U_WB, Wa, ws + O_TWH);
  k_stats<<<dim3(64), dim3(256), 0, stream>>>(ws + O_TWH, ws + O_RMAX, ws + O_RDEN);
  k_cipart<<<dim3(1024), dim3(256), 0, stream>>>(h, ws + O_TWH, ws + O_RMAX, ws + O_CIP);
  k_cired<<<dim3(64), dim3(256), 0, stream>>>(ws + O_CIP, ws + O_RDEN, ws + O_CI);
  k_const<<<dim3(64), dim3(256), 0, stream>>>(h, ws + O_CI, Wihg, bihg, bhhg,
                                              Wihr, bihr, bhhr, Winit, binit,
                                              ws + O_GIC, ws + O_RIC, ws + O_S0);
  k_loop<<<dim3(64), dim3(512), 0, stream>>>(ws + O_GIC, ws + O_RIC, ws + O_S0, bhhg,
                                             us + U_BG, ws + O_RWS, ws + O_RWY,
                                             ws + O_SG, ws + O_LP,
                                             (unsigned int*)(ws + O_CTR),
                                             out);
}

// Round 8
// 452.911 us; speedup vs baseline: 1.1650x; 1.0437x over previous
//
#include <hip/hip_runtime.h>
#include <cstdint>

typedef unsigned short ushort_t;
typedef __attribute__((ext_vector_type(8))) short short8;
typedef __attribute__((ext_vector_type(4))) short short4_t;
typedef __attribute__((ext_vector_type(4))) float f4;

#define BB   64
#define TT   2048
#define DD   256
#define DO_  128
#define OL   64

// ---- workspace layout (float indices) ----
#define O_TWH   0                 // 131072
#define O_RMAX  131072            // 64
#define O_RDEN  131136            // 64
#define O_CIP   131200            // 262144
#define O_CI    393344            // 16384
#define O_GIC   409728            // 49152
#define O_RIC   458880            // 8192
#define O_S0    467072            // 16384
#define O_SG    483456            // s exchange [2][64 batch][256] = 32768
#define O_LP    516224            // logit partials [2][8 grp][8 bb][8 q][128 m] = 131072
#define O_CTR   647296            // (unused now)
#define O_RWS   647808            // RWS_g [8 blk][32 kl][128 m] fp32 = 32768
#define O_RWY   680576            // RWY_g [8 blk][16 jl][128 m] fp32 = 16384
#define O_US    696960            // ushort region base (byte 2787840, 16B aligned)
#define U_WB    0                 // 65536: bf16 W_h_a row-major
#define U_BG    65536             // 294912: gate B [blk][n 6][kb 12][lane 64][pos 8]

static __device__ __forceinline__ ushort_t f2bf(float f) {
  union { float f; uint32_t u; } v; v.f = f;
  uint32_t u = v.u;
  u += 0x7FFFu + ((u >> 16) & 1u);   // RNE
  return (ushort_t)(u >> 16);
}
static __device__ __forceinline__ uint32_t fbits(float f) {
  union { float f; uint32_t u; } v; v.f = f; return v.u;
}
static __device__ __forceinline__ float fast_tanh(float x) {
  float e = __expf(2.f * x);
  return 1.f - 2.f / (e + 1.f);
}
static __device__ __forceinline__ float fast_sigmoid(float x) {
  return 1.f / (1.f + __expf(-x));
}
// LLC-coherent store with 2-bit step-tag embedded in mantissa LSBs
static __device__ __forceinline__ void llc_store_tag(float* p, float v, uint32_t tag) {
  union { float f; uint32_t u; } x; x.f = v;
  x.u = (x.u & ~3u) | tag;
  __hip_atomic_store((uint32_t*)p, x.u, __ATOMIC_RELAXED, __HIP_MEMORY_SCOPE_AGENT);
}

// ---------------- K0: weight repack ----------------
__global__ __launch_bounds__(256) void k_prep(const float* __restrict__ Wha,
    const float* __restrict__ Whhg, const float* __restrict__ Wihg,
    const float* __restrict__ Wihr, const float* __restrict__ Whhr,
    float* __restrict__ ws, ushort_t* __restrict__ us) {
  int idx = blockIdx.x * 256 + threadIdx.x;
  if (idx < 65536) {
    us[U_WB + idx] = f2bf(Wha[idx]);
    return;
  }
  if (idx < 65536 + 294912) {
    int i = idx - 65536;
    int pos = i & 7;
    int l = (i >> 3) & 63;
    int r = i >> 9;              // = ((blk*6+n)*12 + kb)
    int kb = r % 12;
    int r2 = r / 12;
    int n = r2 % 6;
    int blk = r2 / 6;
    int c = n * 16 + (l & 15);   // column 0..95
    int g = c >> 5;              // gate 0:r 1:z 2:n
    int kl = c & 31;
    int kg = 32 * blk + kl;      // global k
    int j = kb * 32 + ((l >> 4) & 3) * 8 + pos;   // input index 0..383
    int row = g * 256 + kg;      // gate row
    float v;
    if (j < 256) v = Whhg[row * 256 + j];        // s-input
    else         v = Wihg[row * 384 + j];        // y-input (cols 256..383)
    us[U_BG + i] = f2bf(v);
    return;
  }
  if (idx < 65536 + 294912 + 32768) {
    int i = idx - (65536 + 294912);
    int m = i & 127, kl = (i >> 7) & 31, blk = i >> 12;
    ws[O_RWS + i] = Wihr[m * 512 + 256 + 32 * blk + kl];
  } else {
    int i = idx - (65536 + 294912 + 32768);
    int m = i & 127, jl = (i >> 7) & 15, blk = i >> 11;
    ws[O_RWY + i] = Whhr[m * 128 + 16 * blk + jl];
  }
}

// ---------------- K1: twh[b,t] = sum_h tanh(h.Wha^T) * wa1 (MFMA) ----------------
__global__ __launch_bounds__(256) void k_twh(const float* __restrict__ h,
                                             const ushort_t* __restrict__ Wb,
                                             const float* __restrict__ Wa,
                                             float* __restrict__ twh) {
  __shared__ __align__(16) ushort_t alds[64 * 264];
  __shared__ float walds[256];
  const int tid = threadIdx.x;
  const long rowbase = (long)blockIdx.x * 64;
  walds[tid] = Wa[tid];
  for (int it = 0; it < 8; ++it) {
    int q = it * 256 + tid;
    int r = q >> 5;
    int c8 = q & 31;
    const float* src = h + (rowbase + r) * 256 + c8 * 8;
    float4 a = *(const float4*)(src);
    float4 b = *(const float4*)(src + 4);
    union { ushort_t u[8]; short8 v; } t;
    t.u[0]=f2bf(a.x); t.u[1]=f2bf(a.y); t.u[2]=f2bf(a.z); t.u[3]=f2bf(a.w);
    t.u[4]=f2bf(b.x); t.u[5]=f2bf(b.y); t.u[6]=f2bf(b.z); t.u[7]=f2bf(b.w);
    *(short8*)&alds[r * 264 + c8 * 8] = t.v;
  }
  __syncthreads();
  const int l = tid & 63, w = tid >> 6;
  const int cres = l & 15, kg = l >> 4;
  f4 acc[16];
  #pragma unroll
  for (int f = 0; f < 16; ++f) acc[f] = (f4){0.f, 0.f, 0.f, 0.f};
  const int arow = 16 * w + cres;
  #pragma unroll
  for (int ks = 0; ks < 8; ++ks) {
    short8 af = *(const short8*)&alds[arow * 264 + ks * 32 + kg * 8];
    const ushort_t* bp = Wb + ks * 32 + kg * 8 + cres * 256;
    #pragma unroll
    for (int f = 0; f < 16; ++f) {
      short8 bf = *(const short8*)(bp + f * 16 * 256);
      acc[f] = __builtin_amdgcn_mfma_f32_16x16x32_bf16(af, bf, acc[f], 0, 0, 0);
    }
  }
  float t4[4] = {0.f, 0.f, 0.f, 0.f};
  #pragma unroll
  for (int f = 0; f < 16; ++f) {
    float wa = walds[16 * f + cres];
    #pragma unroll
    for (int r = 0; r < 4; ++r) t4[r] += fast_tanh(acc[f][r]) * wa;
  }
  #pragma unroll
  for (int m = 1; m <= 8; m <<= 1) {
    #pragma unroll
    for (int r = 0; r < 4; ++r) t4[r] += __shfl_xor(t4[r], m);
  }
  if (cres == 0) {
    #pragma unroll
    for (int r = 0; r < 4; ++r)
      twh[rowbase + 16 * w + kg * 4 + r] = t4[r];
  }
}

// ---------------- K2a ----------------
__global__ __launch_bounds__(256) void k_stats(const float* __restrict__ twh,
                                               float* __restrict__ rmax,
                                               float* __restrict__ rden) {
  __shared__ float redm[4], reds[4];
  const int b = blockIdx.x, tid = threadIdx.x;
  float v[8];
  #pragma unroll
  for (int j = 0; j < 8; ++j) v[j] = twh[b * 2048 + tid + j * 256];
  float mx = v[0];
  #pragma unroll
  for (int j = 1; j < 8; ++j) mx = fmaxf(mx, v[j]);
  #pragma unroll
  for (int d = 32; d >= 1; d >>= 1) mx = fmaxf(mx, __shfl_xor(mx, d));
  if ((tid & 63) == 0) redm[tid >> 6] = mx;
  __syncthreads();
  float M = fmaxf(fmaxf(redm[0], redm[1]), fmaxf(redm[2], redm[3]));
  float s = 0.f;
  #pragma unroll
  for (int j = 0; j < 8; ++j) s += __expf(v[j] - M);
  #pragma unroll
  for (int d = 32; d >= 1; d >>= 1) s += __shfl_xor(s, d);
  if ((tid & 63) == 0) reds[tid >> 6] = s;
  __syncthreads();
  if (tid == 0) { rmax[b] = M; rden[b] = reds[0] + reds[1] + reds[2] + reds[3]; }
}

// ---------------- K2b ----------------
__global__ __launch_bounds__(256) void k_cipart(const float* __restrict__ h,
                                                const float* __restrict__ twh,
                                                const float* __restrict__ rmax,
                                                float* __restrict__ cipart) {
  __shared__ float p[128];
  const int b = blockIdx.x >> 4, ts = blockIdx.x & 15;
  const int tid = threadIdx.x;
  const int t0 = ts * 128;
  if (tid < 128) p[tid] = __expf(twh[b * 2048 + t0 + tid] - rmax[b]);
  __syncthreads();
  float acc = 0.f;
  const float* hp = h + ((long)(b * 2048 + t0)) * 256 + tid;
  #pragma unroll 8
  for (int i = 0; i < 128; ++i) { acc += p[i] * hp[0]; hp += 256; }
  cipart[(b * 16 + ts) * 256 + tid] = acc;
}

// ---------------- K2c ----------------
__global__ __launch_bounds__(256) void k_cired(const float* __restrict__ cipart,
                                               const float* __restrict__ rden,
                                               float* __restrict__ ci) {
  const int b = blockIdx.x, d = threadIdx.x;
  float a = 0.f;
  #pragma unroll
  for (int ts = 0; ts < 16; ++ts) a += cipart[(b * 16 + ts) * 256 + d];
  ci[b * 256 + d] = a / rden[b];
}

// ---------------- K3 ----------------
__global__ __launch_bounds__(256) void k_const(const float* __restrict__ h,
    const float* __restrict__ ci,
    const float* __restrict__ Wihg, const float* __restrict__ bihg,
    const float* __restrict__ bhhg,
    const float* __restrict__ Wihr, const float* __restrict__ bihr,
    const float* __restrict__ bhhr,
    const float* __restrict__ Winit, const float* __restrict__ binit,
    float* __restrict__ gic, float* __restrict__ ric, float* __restrict__ s0) {
  __shared__ float cil[256], h0l[256];
  const int b = blockIdx.x, tid = threadIdx.x;
  cil[tid] = ci[b * 256 + tid];
  h0l[tid] = h[(long)b * 2048 * 256 + tid];
  __syncthreads();
  const int k = tid;
  #pragma unroll
  for (int g = 0; g < 3; ++g) {
    float a = bihg[g * 256 + k] + (g < 2 ? bhhg[g * 256 + k] : 0.f);
    const float* wp = Wihg + (long)(g * 256 + k) * 384;
    for (int d = 0; d < 256; d += 4) {
      float4 w4 = *(const float4*)(wp + d);
      a += cil[d] * w4.x + cil[d + 1] * w4.y + cil[d + 2] * w4.z + cil[d + 3] * w4.w;
    }
    gic[b * 768 + g * 256 + k] = a;
  }
  {
    float a = binit[k];
    const float* wp = Winit + (long)k * 256;
    for (int d = 0; d < 256; d += 4) {
      float4 w4 = *(const float4*)(wp + d);
      a += h0l[d] * w4.x + h0l[d + 1] * w4.y + h0l[d + 2] * w4.z + h0l[d + 3] * w4.w;
    }
    s0[b * 256 + k] = fast_tanh(a);
  }
  if (tid < 128) {
    int m = tid;
    float a = bihr[m] + bhhr[m];
    const float* wp = Wihr + (long)m * 512;
    for (int d = 0; d < 256; d += 4) {
      float4 w4 = *(const float4*)(wp + d);
      a += cil[d] * w4.x + cil[d + 1] * w4.y + cil[d + 2] * w4.z + cil[d + 3] * w4.w;
    }
    ric[b * 128 + m] = a;
  }
}

// ---------------- K4: 64-step recurrence, LDS weights, TAGGED dataflow sync --
// 64 blocks = 8 groups x 8 blocks. NO barrier counter: every exchanged fp32
// word carries a 2-bit step tag in its mantissa LSBs (<=4ulp noise). Readers
// poll their batched 17-load window until all 20 tags match (it>>1)&3.
// Buffers double-buffered by step parity; 2-bit tag disambiguates generations
// (group skew bounded at 1 step by the full-s dependency in phase 5).
__global__ __launch_bounds__(512) void k_loop(
    const float* __restrict__ gic, const float* __restrict__ ric,
    const float* __restrict__ s0w, const float* __restrict__ bhhg,
    const ushort_t* __restrict__ BG, const float* __restrict__ RWSg,
    const float* __restrict__ RWYg,
    float* __restrict__ sg, float* __restrict__ lp,
    float* __restrict__ out) {
  __shared__ __align__(16) ushort_t Bl[36864];   // [n6][kb12][lane64][8] 73728B
  __shared__ __align__(16) ushort_t Al[6144];    // [kb12][kg4][row16][8] 12288B
  __shared__ float RWSl[32][128];
  __shared__ float RWYl[16][128];
  __shared__ float gsum[8][128];                 // r | z | nh | ni
  __shared__ float sslice[8][32];
  __shared__ float ybuf[8][128];
  __shared__ float ricl[8][128];
  __shared__ float gicl[8][3][32];
  __shared__ float bnl[32];
  const int tid = threadIdx.x;
  const int grp = blockIdx.x & 7;
  const int blk = blockIdx.x >> 3;
  const int b0 = grp * 8;

  // ---- one-time LDS fills ----
  {
    const short8* src = (const short8*)(BG + (long)blk * 36864);
    short8* dst = (short8*)Bl;
    for (int i = tid; i < 4608; i += 512) dst[i] = src[i];
  }
  for (int i = tid; i < 4096; i += 512) ((float*)RWSl)[i] = RWSg[blk * 4096 + i];
  for (int i = tid; i < 2048; i += 512) ((float*)RWYl)[i] = RWYg[blk * 2048 + i];
  for (int i = tid; i < 1024; i += 512) ((float*)ricl)[i] = ric[b0 * 128 + i];
  for (int i = tid; i < 768; i += 512) {
    int bb = i / 96, rem = i % 96, g = rem >> 5, kl = rem & 31;
    gicl[bb][g][kl] = gic[(b0 + bb) * 768 + g * 256 + blk * 32 + kl];
  }
  if (tid < 32) bnl[tid] = bhhg[512 + blk * 32 + tid];
  if (tid < 256) {
    int bb = tid >> 5, kl = tid & 31;
    sslice[bb][kl] = s0w[(b0 + bb) * 256 + blk * 32 + kl];
  }
  for (int i = tid; i < 1024; i += 512) ((float*)ybuf)[i] = 0.f;
  // zero A pad rows 8..15 (stay zero forever)
  for (int i = tid; i < 3072; i += 512) {
    int kb = i >> 8, rem = i & 255, kg = rem >> 6, row = 8 + ((rem >> 3) & 7), pos = rem & 7;
    Al[((kb * 4 + kg) * 16 + row) * 8 + pos] = 0;
  }
  __syncthreads();

  for (int it = 0; it <= OL; ++it) {
    const int par = it & 1;
    const int bb1 = tid >> 6, ml = tid & 63;
    f4 sgv;
    // ---- phase 1: tag-polled batched LLC reads; softmax of prev logits ----
    if (it > 0) {
      const uint32_t texp = (((uint32_t)it) >> 1) & 3u;
      const float* aL = lp + (((long)((par * 8 + grp) * 8 + bb1)) << 10) + ml;
      const float* a2 = sg + par * 16384 + (b0 + bb1) * 256 + ml * 4;
      float r0,r1,r2,r3,r4,r5,r6,r7,r8,r9,r10,r11,r12,r13,r14,r15;
      while (true) {
        asm volatile(
          "global_load_dword %0, %17, off sc0 sc1\n\t"
          "global_load_dword %1, %17, off offset:512 sc0 sc1\n\t"
          "global_load_dword %2, %17, off offset:1024 sc0 sc1\n\t"
          "global_load_dword %3, %17, off offset:1536 sc0 sc1\n\t"
          "global_load_dword %4, %17, off offset:2048 sc0 sc1\n\t"
          "global_load_dword %5, %17, off offset:2560 sc0 sc1\n\t"
          "global_load_dword %6, %17, off offset:3072 sc0 sc1\n\t"
          "global_load_dword %7, %17, off offset:3584 sc0 sc1\n\t"
          "global_load_dword %8, %17, off offset:256 sc0 sc1\n\t"
          "global_load_dword %9, %17, off offset:768 sc0 sc1\n\t"
          "global_load_dword %10, %17, off offset:1280 sc0 sc1\n\t"
          "global_load_dword %11, %17, off offset:1792 sc0 sc1\n\t"
          "global_load_dword %12, %17, off offset:2304 sc0 sc1\n\t"
          "global_load_dword %13, %17, off offset:2816 sc0 sc1\n\t"
          "global_load_dword %14, %17, off offset:3328 sc0 sc1\n\t"
          "global_load_dword %15, %17, off offset:3840 sc0 sc1\n\t"
          "global_load_dwordx4 %16, %18, off sc0 sc1\n\t"
          "s_waitcnt vmcnt(0)"
          : "=&v"(r0), "=&v"(r1), "=&v"(r2), "=&v"(r3),
            "=&v"(r4), "=&v"(r5), "=&v"(r6), "=&v"(r7),
            "=&v"(r8), "=&v"(r9), "=&v"(r10), "=&v"(r11),
            "=&v"(r12), "=&v"(r13), "=&v"(r14), "=&v"(r15),
            "=&v"(sgv)
          : "v"(aL), "v"(a2)
          : "memory");
        uint32_t bad = (fbits(r0) ^ texp) | (fbits(r1) ^ texp) |
                       (fbits(r2) ^ texp) | (fbits(r3) ^ texp) |
                       (fbits(r4) ^ texp) | (fbits(r5) ^ texp) |
                       (fbits(r6) ^ texp) | (fbits(r7) ^ texp) |
                       (fbits(r8) ^ texp) | (fbits(r9) ^ texp) |
                       (fbits(r10) ^ texp) | (fbits(r11) ^ texp) |
                       (fbits(r12) ^ texp) | (fbits(r13) ^ texp) |
                       (fbits(r14) ^ texp) | (fbits(r15) ^ texp) |
                       (fbits(sgv[0]) ^ texp) | (fbits(sgv[1]) ^ texp) |
                       (fbits(sgv[2]) ^ texp) | (fbits(sgv[3]) ^ texp);
        if ((bad & 3u) == 0u) break;
        __builtin_amdgcn_s_sleep(1);
      }
      float L0 = ricl[bb1][ml]      + ((r0+r1)+(r2+r3)) + ((r4+r5)+(r6+r7));
      float L1 = ricl[bb1][ml + 64] + ((r8+r9)+(r10+r11)) + ((r12+r13)+(r14+r15));
      L0 = fast_tanh(L0); L1 = fast_tanh(L1);
      float e0 = __expf(L0), e1 = __expf(L1);
      float s = e0 + e1;
      #pragma unroll
      for (int d = 32; d >= 1; d >>= 1) s += __shfl_xor(s, d);
      float y0 = e0 / s, y1 = e1 / s;
      ybuf[bb1][ml] = y0; ybuf[bb1][ml + 64] = y1;
      if (bb1 == blk) {
        float* op = out + ((long)(b0 + blk) * OL + (it - 1)) * DO_;
        op[ml] = y0; op[ml + 64] = y1;
      }
    } else {
      sgv = *(const f4*)(s0w + (b0 + bb1) * 256 + ml * 4);
    }
    if (it == OL) break;
    __syncthreads();
    // ---- phase 3: build A (bf16) rows=batch, cols 0..255=s, 256..383=y ----
    {
      const int j4 = ml * 4;
      int kb = j4 >> 5, kg = (j4 >> 3) & 3, pos = j4 & 7;
      short4_t h4;
      h4[0] = (short)f2bf(sgv[0]); h4[1] = (short)f2bf(sgv[1]);
      h4[2] = (short)f2bf(sgv[2]); h4[3] = (short)f2bf(sgv[3]);
      *(short4_t*)&Al[((kb * 4 + kg) * 16 + bb1) * 8 + pos] = h4;
    }
    if (tid < 256) {
      const int bb = tid >> 5, jl4 = (tid & 31) * 4;
      const int j = 256 + jl4;
      int kb = j >> 5, kg = (j >> 3) & 3, pos = j & 7;
      short4_t h4;
      h4[0] = (short)f2bf(ybuf[bb][jl4]);     h4[1] = (short)f2bf(ybuf[bb][jl4 + 1]);
      h4[2] = (short)f2bf(ybuf[bb][jl4 + 2]); h4[3] = (short)f2bf(ybuf[bb][jl4 + 3]);
      *(short4_t*)&Al[((kb * 4 + kg) * 16 + bb) * 8 + pos] = h4;
    }
    __syncthreads();
    // ---- phase 5: gate MFMA (waves 0,1), K-split stash separates nh/ni ----
    if (tid < 128) {
      const int w = tid >> 6, l = tid & 63;
      f4 a0 = (f4){0,0,0,0}, a1 = (f4){0,0,0,0}, a2v = (f4){0,0,0,0};
      f4 m1 = (f4){0,0,0,0}, m2 = (f4){0,0,0,0};
      const short8* Ap = (const short8*)Al + l;
      const short8* Bp = (const short8*)Bl + (w * 3) * 768 + l;
      #pragma unroll
      for (int kb = 0; kb < 12; ++kb) {
        short8 af = Ap[kb * 64];
        a0 = __builtin_amdgcn_mfma_f32_16x16x32_bf16(af, Bp[kb * 64], a0, 0, 0, 0);
        a1 = __builtin_amdgcn_mfma_f32_16x16x32_bf16(af, Bp[768 + kb * 64], a1, 0, 0, 0);
        a2v = __builtin_amdgcn_mfma_f32_16x16x32_bf16(af, Bp[1536 + kb * 64], a2v, 0, 0, 0);
        if (kb == 7) { m1 = a1; m2 = a2v; }   // s-part only (used by wave 1)
      }
      if (l < 32) {
        const int bbase = (l >> 4) * 4, c = l & 15;
        if (w == 0) {
          #pragma unroll
          for (int r = 0; r < 4; ++r) {
            gsum[bbase + r][c]      = a0[r];
            gsum[bbase + r][16 + c] = a1[r];
            gsum[bbase + r][32 + c] = a2v[r];
          }
        } else {
          #pragma unroll
          for (int r = 0; r < 4; ++r) {
            gsum[bbase + r][48 + c] = a0[r];          // z hi
            gsum[bbase + r][64 + c]      = m1[r];     // nh lo  (s-part)
            gsum[bbase + r][96 + c]      = a1[r] - m1[r]; // ni lo (y-part)
            gsum[bbase + r][64 + 16 + c] = m2[r];     // nh hi
            gsum[bbase + r][96 + 16 + c] = a2v[r] - m2[r]; // ni hi
          }
        }
      }
    }
    __syncthreads();
    // ---- phase 7: GRU update for k-slice (tagged store of snew) ----
    {
      const uint32_t tprod = (((uint32_t)it + 1u) >> 1) & 3u;
      if (tid < 256) {
        const int bb = tid >> 5, kl = tid & 31;
        float sold = sslice[bb][kl];
        float R   = fast_sigmoid(gsum[bb][kl]      + gicl[bb][0][kl]);
        float Z   = fast_sigmoid(gsum[bb][32 + kl] + gicl[bb][1][kl]);
        float hn  = gsum[bb][64 + kl] + bnl[kl];
        float in_ = gsum[bb][96 + kl] + gicl[bb][2][kl];
        float N = fast_tanh(in_ + R * hn);
        float sn = (1.f - Z) * N + Z * sold;
        sslice[bb][kl] = sn;
        llc_store_tag(sg + (par ^ 1) * 16384 + (b0 + bb) * 256 + blk * 32 + kl, sn, tprod);
      }
    }
    __syncthreads();
    // ---- phase 9: RNN logit partials (tagged, coalesced 128-chunks) ----
    {
      const uint32_t tprod = (((uint32_t)it + 1u) >> 1) & 3u;
      const int m = tid & 127, q = tid >> 7;
      const int ba = 2 * q, bbv = 2 * q + 1;
      float acc0 = 0.f, acc1 = 0.f;
      #pragma unroll 8
      for (int kl = 0; kl < 32; ++kl) {
        float w = RWSl[kl][m];
        acc0 += w * sslice[ba][kl];
        acc1 += w * sslice[bbv][kl];
      }
      #pragma unroll 8
      for (int jl = 0; jl < 16; ++jl) {
        float w = RWYl[jl][m];
        acc0 += w * ybuf[ba][16 * blk + jl];
        acc1 += w * ybuf[bbv][16 * blk + jl];
      }
      // layout [par][grp][bb][q][m]: q=blk chunk of 128 floats (coalesced)
      float* dst = lp + (((long)((par ^ 1) * 8 + grp) * 8) << 10) + blk * 128 + m;
      llc_store_tag(dst + (ba  << 10), acc0, tprod);
      llc_store_tag(dst + (bbv << 10), acc1, tprod);
    }
    // ---- end of step: intra-block sync only (no global barrier) ----
    __syncthreads();
  }
}

extern "C" void kernel_launch(void* const* d_in, const int* in_sizes, int n_in,
                              void* d_out, int out_size, void* d_ws, size_t ws_size,
                              hipStream_t stream) {
  const float* h     = (const float*)d_in[0];
  const float* Wha   = (const float*)d_in[1];
  const float* Wa    = (const float*)d_in[4];
  const float* Winit = (const float*)d_in[5];
  const float* binit = (const float*)d_in[6];
  const float* Wihg  = (const float*)d_in[7];
  const float* Whhg  = (const float*)d_in[8];
  const float* bihg  = (const float*)d_in[9];
  const float* bhhg  = (const float*)d_in[10];
  const float* Wihr  = (const float*)d_in[11];
  const float* Whhr  = (const float*)d_in[12];
  const float* bihr  = (const float*)d_in[13];
  const float* bhhr  = (const float*)d_in[14];
  float* ws  = (float*)d_ws;
  float* out = (float*)d_out;
  ushort_t* us = (ushort_t*)(ws + O_US);

  // Seed exchange-buffer tags so first-step polls never see a valid tag:
  // par0 buffers -> 0x00 (tag 0), par1 buffers -> 0xFF (tag 3).
  // First reads expect: sg/lp par1 @ it=1 tag0 (!=3), par0 @ it=2 tag1 (!=0).
  hipMemsetAsync((char*)d_ws + (size_t)O_SG * 4,             0x00, 16384 * 4, stream);
  hipMemsetAsync((char*)d_ws + (size_t)(O_SG + 16384) * 4,   0xFF, 16384 * 4, stream);
  hipMemsetAsync((char*)d_ws + (size_t)O_LP * 4,             0x00, 65536 * 4, stream);
  hipMemsetAsync((char*)d_ws + (size_t)(O_LP + 65536) * 4,   0xFF, 65536 * 4, stream);

  k_prep<<<dim3(1600), dim3(256), 0, stream>>>(Wha, Whhg, Wihg, Wihr, Whhr, ws, us);
  k_twh<<<dim3(2048), dim3(256), 0, stream>>>(h, us + U_WB, Wa, ws + O_TWH);
  k_stats<<<dim3(64), dim3(256), 0, stream>>>(ws + O_TWH, ws + O_RMAX, ws + O_RDEN);
  k_cipart<<<dim3(1024), dim3(256), 0, stream>>>(h, ws + O_TWH, ws + O_RMAX, ws + O_CIP);
  k_cired<<<dim3(64), dim3(256), 0, stream>>>(ws + O_CIP, ws + O_RDEN, ws + O_CI);
  k_const<<<dim3(64), dim3(256), 0, stream>>>(h, ws + O_CI, Wihg, bihg, bhhg,
                                              Wihr, bihr, bhhr, Winit, binit,
                                              ws + O_GIC, ws + O_RIC, ws + O_S0);
  k_loop<<<dim3(64), dim3(512), 0, stream>>>(ws + O_GIC, ws + O_RIC, ws + O_S0, bhhg,
                                             us + U_BG, ws + O_RWS, ws + O_RWY,
                                             ws + O_SG, ws + O_LP,
                                             out);
}

// Round 11
// 403.274 us; speedup vs baseline: 1.3084x; 1.1231x over previous
//
#include <hip/hip_runtime.h>
#include <cstdint>

typedef unsigned short ushort_t;
typedef __attribute__((ext_vector_type(8))) short short8;
typedef __attribute__((ext_vector_type(4))) short short4_t;
typedef __attribute__((ext_vector_type(4))) float f4;

#define BB   64
#define TT   2048
#define DD   256
#define DO_  128
#define OL   64

// ---- workspace layout (float indices) ----
#define O_TWH   0                 // 131072
#define O_PDEN  131072            // 1024 (64 b x 16 ts partial softmax denoms)
#define O_CIP   132096            // 262144  (was 131200: OVERLAPPED pden -> r9/r10 failures)
#define O_GIC   409728            // 49152
#define O_RIC   458880            // 8192
#define O_S0    467072            // 16384
#define O_SG    483456            // s exchange [2][64 batch][256] = 32768
#define O_LP    516224            // logit partials [2][8 grp][8 bb][8 q][128 m] = 131072
#define O_RWS   647808            // RWS_g [8 blk][32 kl][128 m] fp32 = 32768
#define O_RWY   680576            // RWY_g [8 blk][16 jl][128 m] fp32 = 16384
#define O_US    696960            // ushort region base (byte 2787840, 16B aligned)
#define U_WB    0                 // 65536: bf16 W_h_a row-major
#define U_BG    65536             // 294912: gate B [blk][n 6][kb 12][lane 64][pos 8]

static __device__ __forceinline__ ushort_t f2bf(float f) {
  union { float f; uint32_t u; } v; v.f = f;
  uint32_t u = v.u;
  u += 0x7FFFu + ((u >> 16) & 1u);   // RNE
  return (ushort_t)(u >> 16);
}
static __device__ __forceinline__ uint32_t fbits(float f) {
  union { float f; uint32_t u; } v; v.f = f; return v.u;
}
static __device__ __forceinline__ float fast_tanh(float x) {
  float e = __expf(2.f * x);
  return 1.f - 2.f / (e + 1.f);
}
static __device__ __forceinline__ float fast_sigmoid(float x) {
  return 1.f / (1.f + __expf(-x));
}
// LLC-coherent store with 2-bit step-tag embedded in mantissa LSBs
static __device__ __forceinline__ void llc_store_tag(float* p, float v, uint32_t tag) {
  union { float f; uint32_t u; } x; x.f = v;
  x.u = (x.u & ~3u) | tag;
  __hip_atomic_store((uint32_t*)p, x.u, __ATOMIC_RELAXED, __HIP_MEMORY_SCOPE_AGENT);
}
static __device__ __forceinline__ void llc_store_u32(uint32_t* p, uint32_t v) {
  __hip_atomic_store(p, v, __ATOMIC_RELAXED, __HIP_MEMORY_SCOPE_AGENT);
}

// ---------------- K0: weight repack + exchange-buffer tag seeding ----------------
// items: 65536 Wha + 294912 BG + 32768 RWS + 16384 RWY + 32768 SGseed + 131072 LPseed
//      = 573440 -> grid 2240
__global__ __launch_bounds__(256) void k_prep(const float* __restrict__ Wha,
    const float* __restrict__ Whhg, const float* __restrict__ Wihg,
    const float* __restrict__ Wihr, const float* __restrict__ Whhr,
    float* __restrict__ ws, ushort_t* __restrict__ us) {
  int idx = blockIdx.x * 256 + threadIdx.x;
  if (idx < 65536) {
    us[U_WB + idx] = f2bf(Wha[idx]);
    return;
  }
  if (idx < 65536 + 294912) {
    int i = idx - 65536;
    int pos = i & 7;
    int l = (i >> 3) & 63;
    int r = i >> 9;              // = ((blk*6+n)*12 + kb)
    int kb = r % 12;
    int r2 = r / 12;
    int n = r2 % 6;
    int blk = r2 / 6;
    int c = n * 16 + (l & 15);   // column 0..95
    int g = c >> 5;              // gate 0:r 1:z 2:n
    int kl = c & 31;
    int kg = 32 * blk + kl;      // global k
    int j = kb * 32 + ((l >> 4) & 3) * 8 + pos;   // input index 0..383
    int row = g * 256 + kg;      // gate row
    float v;
    if (j < 256) v = Whhg[row * 256 + j];        // s-input
    else         v = Wihg[row * 384 + j];        // y-input (cols 256..383)
    us[U_BG + i] = f2bf(v);
    return;
  }
  if (idx < 65536 + 294912 + 32768) {
    int i = idx - (65536 + 294912);
    int m = i & 127, kl = (i >> 7) & 31, blk = i >> 12;
    ws[O_RWS + i] = Wihr[m * 512 + 256 + 32 * blk + kl];
    return;
  }
  if (idx < 65536 + 294912 + 32768 + 16384) {
    int i = idx - (65536 + 294912 + 32768);
    int m = i & 127, jl = (i >> 7) & 15, blk = i >> 11;
    ws[O_RWY + i] = Whhr[m * 128 + 16 * blk + jl];
    return;
  }
  if (idx < 409600 + 32768) {
    // SG seeds via LLC-direct stores (same path as k_loop's sc1 readers):
    // par0 -> tag0 pattern, par1 -> 0xFFFFFFFF (tag 3)
    int i = idx - 409600;
    llc_store_u32((uint32_t*)(ws + O_SG) + i, (i < 16384) ? 0u : 0xFFFFFFFFu);
    return;
  }
  {
    int i = idx - (409600 + 32768);   // LP seeds
    llc_store_u32((uint32_t*)(ws + O_LP) + i, (i < 65536) ? 0u : 0xFFFFFFFFu);
  }
}

// ---------------- K1: twh[b,t] = sum_h tanh(h.Wha^T) * wa1 (MFMA, LDS-staged B) --
// B-tile pad stride 40 shorts = 80 B = 5x16: rows 16B-aligned for ds_*_b128,
// <=2-way bank aliasing (free).
__global__ __launch_bounds__(256) void k_twh(const float* __restrict__ h,
                                             const ushort_t* __restrict__ Wb,
                                             const float* __restrict__ Wa,
                                             float* __restrict__ twh) {
  __shared__ __align__(16) ushort_t alds[64 * 264];
  __shared__ __align__(16) ushort_t blds[256 * 40];
  __shared__ float walds[256];
  const int tid = threadIdx.x;
  const long rowbase = (long)blockIdx.x * 64;
  walds[tid] = Wa[tid];
  for (int it = 0; it < 8; ++it) {
    int q = it * 256 + tid;
    int r = q >> 5;
    int c8 = q & 31;
    const float* src = h + (rowbase + r) * 256 + c8 * 8;
    float4 a = *(const float4*)(src);
    float4 b = *(const float4*)(src + 4);
    union { ushort_t u[8]; short8 v; } t;
    t.u[0]=f2bf(a.x); t.u[1]=f2bf(a.y); t.u[2]=f2bf(a.z); t.u[3]=f2bf(a.w);
    t.u[4]=f2bf(b.x); t.u[5]=f2bf(b.y); t.u[6]=f2bf(b.z); t.u[7]=f2bf(b.w);
    *(short8*)&alds[r * 264 + c8 * 8] = t.v;
  }
  __syncthreads();
  const int l = tid & 63, w = tid >> 6;
  const int cres = l & 15, kg = l >> 4;
  f4 acc[16];
  #pragma unroll
  for (int f = 0; f < 16; ++f) acc[f] = (f4){0.f, 0.f, 0.f, 0.f};
  const int arow = 16 * w + cres;
  for (int ks = 0; ks < 8; ++ks) {
    // stage B tile: all 256 rows x 32 k (16KB), read once per block
    #pragma unroll
    for (int i = 0; i < 4; ++i) {
      int lin = i * 256 + tid;            // short8 units, 0..1023
      int r = lin >> 2, c8 = (lin & 3) * 8;
      *(short8*)&blds[r * 40 + c8] = *(const short8*)(Wb + r * 256 + ks * 32 + c8);
    }
    __syncthreads();
    short8 af = *(const short8*)&alds[arow * 264 + ks * 32 + kg * 8];
    #pragma unroll
    for (int f = 0; f < 16; ++f) {
      short8 bf = *(const short8*)&blds[(f * 16 + cres) * 40 + kg * 8];
      acc[f] = __builtin_amdgcn_mfma_f32_16x16x32_bf16(af, bf, acc[f], 0, 0, 0);
    }
    __syncthreads();
  }
  float t4[4] = {0.f, 0.f, 0.f, 0.f};
  #pragma unroll
  for (int f = 0; f < 16; ++f) {
    float wa = walds[16 * f + cres];
    #pragma unroll
    for (int r = 0; r < 4; ++r) t4[r] += fast_tanh(acc[f][r]) * wa;
  }
  #pragma unroll
  for (int m = 1; m <= 8; m <<= 1) {
    #pragma unroll
    for (int r = 0; r < 4; ++r) t4[r] += __shfl_xor(t4[r], m);
  }
  if (cres == 0) {
    #pragma unroll
    for (int r = 0; r < 4; ++r)
      twh[rowbase + 16 * w + kg * 4 + r] = t4[r];
  }
}

// ---------------- K2: fused stats + partial ci (grid 1024 = 64 b x 16 ts) ----------
__global__ __launch_bounds__(256) void k_cipart2(const float* __restrict__ h,
                                                 const float* __restrict__ twh,
                                                 float* __restrict__ cipart,
                                                 float* __restrict__ pden) {
  __shared__ float p[128];
  __shared__ float redm[4];
  __shared__ float redd[2];
  const int b = blockIdx.x >> 4, ts = blockIdx.x & 15;
  const int tid = threadIdx.x;
  float v[8];
  #pragma unroll
  for (int j = 0; j < 8; ++j) v[j] = twh[b * 2048 + tid + j * 256];
  float mx = v[0];
  #pragma unroll
  for (int j = 1; j < 8; ++j) mx = fmaxf(mx, v[j]);
  #pragma unroll
  for (int d = 32; d >= 1; d >>= 1) mx = fmaxf(mx, __shfl_xor(mx, d));
  if ((tid & 63) == 0) redm[tid >> 6] = mx;
  __syncthreads();
  float M = fmaxf(fmaxf(redm[0], redm[1]), fmaxf(redm[2], redm[3]));
  if ((tid >> 7) == (ts & 1)) p[tid & 127] = __expf(v[ts >> 1] - M);
  __syncthreads();
  if (tid < 128) {
    float e = p[tid];
    #pragma unroll
    for (int d = 32; d >= 1; d >>= 1) e += __shfl_xor(e, d);
    if ((tid & 63) == 0) redd[tid >> 6] = e;
  }
  __syncthreads();
  if (tid == 0) pden[b * 16 + ts] = redd[0] + redd[1];
  float acc = 0.f;
  const float* hp = h + ((long)(b * 2048 + ts * 128)) * 256 + tid;
  #pragma unroll 8
  for (int i = 0; i < 128; ++i) { acc += p[i] * hp[0]; hp += 256; }
  cipart[(b * 16 + ts) * 256 + tid] = acc;
}

// ---------------- K3: fused ci-reduce + per-batch constants (grid 64) ----------
// LDS-staged weight tiles [256][33] (pad 33: stage coalesced, scalar reads).
__global__ __launch_bounds__(256) void k_cc(const float* __restrict__ h,
    const float* __restrict__ cipart, const float* __restrict__ pden,
    const float* __restrict__ Wihg, const float* __restrict__ bihg,
    const float* __restrict__ bhhg,
    const float* __restrict__ Wihr, const float* __restrict__ bihr,
    const float* __restrict__ bhhr,
    const float* __restrict__ Winit, const float* __restrict__ binit,
    float* __restrict__ gic, float* __restrict__ ric, float* __restrict__ s0) {
  __shared__ float cil[256], h0l[256];
  __shared__ float wt[256][33];
  const int b = blockIdx.x, tid = threadIdx.x;
  {
    float a = 0.f;
    #pragma unroll
    for (int ts = 0; ts < 16; ++ts) a += cipart[(b * 16 + ts) * 256 + tid];
    float den = 0.f;
    #pragma unroll
    for (int ts = 0; ts < 16; ++ts) den += pden[b * 16 + ts];
    cil[tid] = a / den;
    h0l[tid] = h[(long)b * 2048 * 256 + tid];
  }
  __syncthreads();
  // gic (3 gates x 256 outputs)
  for (int g = 0; g < 3; ++g) {
    float acc = bihg[g * 256 + tid] + (g < 2 ? bhhg[g * 256 + tid] : 0.f);
    for (int d0 = 0; d0 < 256; d0 += 32) {
      __syncthreads();
      #pragma unroll
      for (int i = 0; i < 32; ++i) {
        int lin = i * 256 + tid;
        int k = lin >> 5, dd = lin & 31;
        wt[k][dd] = Wihg[(g * 256 + k) * 384 + d0 + dd];
      }
      __syncthreads();
      #pragma unroll
      for (int dd = 0; dd < 32; ++dd) acc += cil[d0 + dd] * wt[tid][dd];
    }
    gic[b * 768 + g * 256 + tid] = acc;
  }
  // s0 (Winit)
  {
    float acc = binit[tid];
    for (int d0 = 0; d0 < 256; d0 += 32) {
      __syncthreads();
      #pragma unroll
      for (int i = 0; i < 32; ++i) {
        int lin = i * 256 + tid;
        int k = lin >> 5, dd = lin & 31;
        wt[k][dd] = Winit[k * 256 + d0 + dd];
      }
      __syncthreads();
      #pragma unroll
      for (int dd = 0; dd < 32; ++dd) acc += h0l[d0 + dd] * wt[tid][dd];
    }
    s0[b * 256 + tid] = fast_tanh(acc);
  }
  // ric (Wihr ci-part, 128 outputs)
  {
    float acc = (tid < 128) ? (bihr[tid] + bhhr[tid]) : 0.f;
    for (int d0 = 0; d0 < 256; d0 += 32) {
      __syncthreads();
      #pragma unroll
      for (int i = 0; i < 16; ++i) {
        int lin = i * 256 + tid;
        int m = lin >> 5, dd = lin & 31;
        wt[m][dd] = Wihr[m * 512 + d0 + dd];
      }
      __syncthreads();
      if (tid < 128) {
        #pragma unroll
        for (int dd = 0; dd < 32; ++dd) acc += cil[d0 + dd] * wt[tid][dd];
      }
    }
    if (tid < 128) ric[b * 128 + tid] = acc;
  }
}

// ---------------- K4: 64-step recurrence, LDS weights, TAGGED dataflow sync --
// (byte-identical to round 8 - known good at 232us)
__global__ __launch_bounds__(512) void k_loop(
    const float* __restrict__ gic, const float* __restrict__ ric,
    const float* __restrict__ s0w, const float* __restrict__ bhhg,
    const ushort_t* __restrict__ BG, const float* __restrict__ RWSg,
    const float* __restrict__ RWYg,
    float* __restrict__ sg, float* __restrict__ lp,
    float* __restrict__ out) {
  __shared__ __align__(16) ushort_t Bl[36864];   // [n6][kb12][lane64][8] 73728B
  __shared__ __align__(16) ushort_t Al[6144];    // [kb12][kg4][row16][8] 12288B
  __shared__ float RWSl[32][128];
  __shared__ float RWYl[16][128];
  __shared__ float gsum[8][128];                 // r | z | nh | ni
  __shared__ float sslice[8][32];
  __shared__ float ybuf[8][128];
  __shared__ float ricl[8][128];
  __shared__ float gicl[8][3][32];
  __shared__ float bnl[32];
  const int tid = threadIdx.x;
  const int grp = blockIdx.x & 7;
  const int blk = blockIdx.x >> 3;
  const int b0 = grp * 8;

  // ---- one-time LDS fills ----
  {
    const short8* src = (const short8*)(BG + (long)blk * 36864);
    short8* dst = (short8*)Bl;
    for (int i = tid; i < 4608; i += 512) dst[i] = src[i];
  }
  for (int i = tid; i < 4096; i += 512) ((float*)RWSl)[i] = RWSg[blk * 4096 + i];
  for (int i = tid; i < 2048; i += 512) ((float*)RWYl)[i] = RWYg[blk * 2048 + i];
  for (int i = tid; i < 1024; i += 512) ((float*)ricl)[i] = ric[b0 * 128 + i];
  for (int i = tid; i < 768; i += 512) {
    int bb = i / 96, rem = i % 96, g = rem >> 5, kl = rem & 31;
    gicl[bb][g][kl] = gic[(b0 + bb) * 768 + g * 256 + blk * 32 + kl];
  }
  if (tid < 32) bnl[tid] = bhhg[512 + blk * 32 + tid];
  if (tid < 256) {
    int bb = tid >> 5, kl = tid & 31;
    sslice[bb][kl] = s0w[(b0 + bb) * 256 + blk * 32 + kl];
  }
  for (int i = tid; i < 1024; i += 512) ((float*)ybuf)[i] = 0.f;
  // zero A pad rows 8..15 (stay zero forever)
  for (int i = tid; i < 3072; i += 512) {
    int kb = i >> 8, rem = i & 255, kg = rem >> 6, row = 8 + ((rem >> 3) & 7), pos = rem & 7;
    Al[((kb * 4 + kg) * 16 + row) * 8 + pos] = 0;
  }
  __syncthreads();

  for (int it = 0; it <= OL; ++it) {
    const int par = it & 1;
    const int bb1 = tid >> 6, ml = tid & 63;
    f4 sgv;
    // ---- phase 1: tag-polled batched LLC reads; softmax of prev logits ----
    if (it > 0) {
      const uint32_t texp = (((uint32_t)it) >> 1) & 3u;
      const float* aL = lp + (((long)((par * 8 + grp) * 8 + bb1)) << 10) + ml;
      const float* a2 = sg + par * 16384 + (b0 + bb1) * 256 + ml * 4;
      float r0,r1,r2,r3,r4,r5,r6,r7,r8,r9,r10,r11,r12,r13,r14,r15;
      while (true) {
        asm volatile(
          "global_load_dword %0, %17, off sc0 sc1\n\t"
          "global_load_dword %1, %17, off offset:512 sc0 sc1\n\t"
          "global_load_dword %2, %17, off offset:1024 sc0 sc1\n\t"
          "global_load_dword %3, %17, off offset:1536 sc0 sc1\n\t"
          "global_load_dword %4, %17, off offset:2048 sc0 sc1\n\t"
          "global_load_dword %5, %17, off offset:2560 sc0 sc1\n\t"
          "global_load_dword %6, %17, off offset:3072 sc0 sc1\n\t"
          "global_load_dword %7, %17, off offset:3584 sc0 sc1\n\t"
          "global_load_dword %8, %17, off offset:256 sc0 sc1\n\t"
          "global_load_dword %9, %17, off offset:768 sc0 sc1\n\t"
          "global_load_dword %10, %17, off offset:1280 sc0 sc1\n\t"
          "global_load_dword %11, %17, off offset:1792 sc0 sc1\n\t"
          "global_load_dword %12, %17, off offset:2304 sc0 sc1\n\t"
          "global_load_dword %13, %17, off offset:2816 sc0 sc1\n\t"
          "global_load_dword %14, %17, off offset:3328 sc0 sc1\n\t"
          "global_load_dword %15, %17, off offset:3840 sc0 sc1\n\t"
          "global_load_dwordx4 %16, %18, off sc0 sc1\n\t"
          "s_waitcnt vmcnt(0)"
          : "=&v"(r0), "=&v"(r1), "=&v"(r2), "=&v"(r3),
            "=&v"(r4), "=&v"(r5), "=&v"(r6), "=&v"(r7),
            "=&v"(r8), "=&v"(r9), "=&v"(r10), "=&v"(r11),
            "=&v"(r12), "=&v"(r13), "=&v"(r14), "=&v"(r15),
            "=&v"(sgv)
          : "v"(aL), "v"(a2)
          : "memory");
        uint32_t bad = (fbits(r0) ^ texp) | (fbits(r1) ^ texp) |
                       (fbits(r2) ^ texp) | (fbits(r3) ^ texp) |
                       (fbits(r4) ^ texp) | (fbits(r5) ^ texp) |
                       (fbits(r6) ^ texp) | (fbits(r7) ^ texp) |
                       (fbits(r8) ^ texp) | (fbits(r9) ^ texp) |
                       (fbits(r10) ^ texp) | (fbits(r11) ^ texp) |
                       (fbits(r12) ^ texp) | (fbits(r13) ^ texp) |
                       (fbits(r14) ^ texp) | (fbits(r15) ^ texp) |
                       (fbits(sgv[0]) ^ texp) | (fbits(sgv[1]) ^ texp) |
                       (fbits(sgv[2]) ^ texp) | (fbits(sgv[3]) ^ texp);
        if ((bad & 3u) == 0u) break;
        __builtin_amdgcn_s_sleep(1);
      }
      float L0 = ricl[bb1][ml]      + ((r0+r1)+(r2+r3)) + ((r4+r5)+(r6+r7));
      float L1 = ricl[bb1][ml + 64] + ((r8+r9)+(r10+r11)) + ((r12+r13)+(r14+r15));
      L0 = fast_tanh(L0); L1 = fast_tanh(L1);
      float e0 = __expf(L0), e1 = __expf(L1);
      float s = e0 + e1;
      #pragma unroll
      for (int d = 32; d >= 1; d >>= 1) s += __shfl_xor(s, d);
      float y0 = e0 / s, y1 = e1 / s;
      ybuf[bb1][ml] = y0; ybuf[bb1][ml + 64] = y1;
      if (bb1 == blk) {
        float* op = out + ((long)(b0 + blk) * OL + (it - 1)) * DO_;
        op[ml] = y0; op[ml + 64] = y1;
      }
    } else {
      sgv = *(const f4*)(s0w + (b0 + bb1) * 256 + ml * 4);
    }
    if (it == OL) break;
    __syncthreads();
    // ---- phase 3: build A (bf16) rows=batch, cols 0..255=s, 256..383=y ----
    {
      const int j4 = ml * 4;
      int kb = j4 >> 5, kg = (j4 >> 3) & 3, pos = j4 & 7;
      short4_t h4;
      h4[0] = (short)f2bf(sgv[0]); h4[1] = (short)f2bf(sgv[1]);
      h4[2] = (short)f2bf(sgv[2]); h4[3] = (short)f2bf(sgv[3]);
      *(short4_t*)&Al[((kb * 4 + kg) * 16 + bb1) * 8 + pos] = h4;
    }
    if (tid < 256) {
      const int bb = tid >> 5, jl4 = (tid & 31) * 4;
      const int j = 256 + jl4;
      int kb = j >> 5, kg = (j >> 3) & 3, pos = j & 7;
      short4_t h4;
      h4[0] = (short)f2bf(ybuf[bb][jl4]);     h4[1] = (short)f2bf(ybuf[bb][jl4 + 1]);
      h4[2] = (short)f2bf(ybuf[bb][jl4 + 2]); h4[3] = (short)f2bf(ybuf[bb][jl4 + 3]);
      *(short4_t*)&Al[((kb * 4 + kg) * 16 + bb) * 8 + pos] = h4;
    }
    __syncthreads();
    // ---- phase 5: gate MFMA (waves 0,1), K-split stash separates nh/ni ----
    if (tid < 128) {
      const int w = tid >> 6, l = tid & 63;
      f4 a0 = (f4){0,0,0,0}, a1 = (f4){0,0,0,0}, a2v = (f4){0,0,0,0};
      f4 m1 = (f4){0,0,0,0}, m2 = (f4){0,0,0,0};
      const short8* Ap = (const short8*)Al + l;
      const short8* Bp = (const short8*)Bl + (w * 3) * 768 + l;
      #pragma unroll
      for (int kb = 0; kb < 12; ++kb) {
        short8 af = Ap[kb * 64];
        a0 = __builtin_amdgcn_mfma_f32_16x16x32_bf16(af, Bp[kb * 64], a0, 0, 0, 0);
        a1 = __builtin_amdgcn_mfma_f32_16x16x32_bf16(af, Bp[768 + kb * 64], a1, 0, 0, 0);
        a2v = __builtin_amdgcn_mfma_f32_16x16x32_bf16(af, Bp[1536 + kb * 64], a2v, 0, 0, 0);
        if (kb == 7) { m1 = a1; m2 = a2v; }   // s-part only (used by wave 1)
      }
      if (l < 32) {
        const int bbase = (l >> 4) * 4, c = l & 15;
        if (w == 0) {
          #pragma unroll
          for (int r = 0; r < 4; ++r) {
            gsum[bbase + r][c]      = a0[r];
            gsum[bbase + r][16 + c] = a1[r];
            gsum[bbase + r][32 + c] = a2v[r];
          }
        } else {
          #pragma unroll
          for (int r = 0; r < 4; ++r) {
            gsum[bbase + r][48 + c] = a0[r];          // z hi
            gsum[bbase + r][64 + c]      = m1[r];     // nh lo  (s-part)
            gsum[bbase + r][96 + c]      = a1[r] - m1[r]; // ni lo (y-part)
            gsum[bbase + r][64 + 16 + c] = m2[r];     // nh hi
            gsum[bbase + r][96 + 16 + c] = a2v[r] - m2[r]; // ni hi
          }
        }
      }
    }
    __syncthreads();
    // ---- phase 7: GRU update for k-slice (tagged store of snew) ----
    {
      const uint32_t tprod = (((uint32_t)it + 1u) >> 1) & 3u;
      if (tid < 256) {
        const int bb = tid >> 5, kl = tid & 31;
        float sold = sslice[bb][kl];
        float R   = fast_sigmoid(gsum[bb][kl]      + gicl[bb][0][kl]);
        float Z   = fast_sigmoid(gsum[bb][32 + kl] + gicl[bb][1][kl]);
        float hn  = gsum[bb][64 + kl] + bnl[kl];
        float in_ = gsum[bb][96 + kl] + gicl[bb][2][kl];
        float N = fast_tanh(in_ + R * hn);
        float sn = (1.f - Z) * N + Z * sold;
        sslice[bb][kl] = sn;
        llc_store_tag(sg + (par ^ 1) * 16384 + (b0 + bb) * 256 + blk * 32 + kl, sn, tprod);
      }
    }
    __syncthreads();
    // ---- phase 9: RNN logit partials (tagged, coalesced 128-chunks) ----
    {
      const uint32_t tprod = (((uint32_t)it + 1u) >> 1) & 3u;
      const int m = tid & 127, q = tid >> 7;
      const int ba = 2 * q, bbv = 2 * q + 1;
      float acc0 = 0.f, acc1 = 0.f;
      #pragma unroll 8
      for (int kl = 0; kl < 32; ++kl) {
        float w = RWSl[kl][m];
        acc0 += w * sslice[ba][kl];
        acc1 += w * sslice[bbv][kl];
      }
      #pragma unroll 8
      for (int jl = 0; jl < 16; ++jl) {
        float w = RWYl[jl][m];
        acc0 += w * ybuf[ba][16 * blk + jl];
        acc1 += w * ybuf[bbv][16 * blk + jl];
      }
      // layout [par][grp][bb][q][m]: q=blk chunk of 128 floats (coalesced)
      float* dst = lp + (((long)((par ^ 1) * 8 + grp) * 8) << 10) + blk * 128 + m;
      llc_store_tag(dst + (ba  << 10), acc0, tprod);
      llc_store_tag(dst + (bbv << 10), acc1, tprod);
    }
    // ---- end of step: intra-block sync only (no global barrier) ----
    __syncthreads();
  }
}

extern "C" void kernel_launch(void* const* d_in, const int* in_sizes, int n_in,
                              void* d_out, int out_size, void* d_ws, size_t ws_size,
                              hipStream_t stream) {
  const float* h     = (const float*)d_in[0];
  const float* Wha   = (const float*)d_in[1];
  const float* Wa    = (const float*)d_in[4];
  const float* Winit = (const float*)d_in[5];
  const float* binit = (const float*)d_in[6];
  const float* Wihg  = (const float*)d_in[7];
  const float* Whhg  = (const float*)d_in[8];
  const float* bihg  = (const float*)d_in[9];
  const float* bhhg  = (const float*)d_in[10];
  const float* Wihr  = (const float*)d_in[11];
  const float* Whhr  = (const float*)d_in[12];
  const float* bihr  = (const float*)d_in[13];
  const float* bhhr  = (const float*)d_in[14];
  float* ws  = (float*)d_ws;
  float* out = (float*)d_out;
  ushort_t* us = (ushort_t*)(ws + O_US);

  k_prep<<<dim3(2240), dim3(256), 0, stream>>>(Wha, Whhg, Wihg, Wihr, Whhr, ws, us);
  k_twh<<<dim3(2048), dim3(256), 0, stream>>>(h, us + U_WB, Wa, ws + O_TWH);
  k_cipart2<<<dim3(1024), dim3(256), 0, stream>>>(h, ws + O_TWH, ws + O_CIP, ws + O_PDEN);
  k_cc<<<dim3(64), dim3(256), 0, stream>>>(h, ws + O_CIP, ws + O_PDEN,
                                           Wihg, bihg, bhhg, Wihr, bihr, bhhr,
                                           Winit, binit,
                                           ws + O_GIC, ws + O_RIC, ws + O_S0);
  k_loop<<<dim3(64), dim3(512), 0, stream>>>(ws + O_GIC, ws + O_RIC, ws + O_S0, bhhg,
                                             us + U_BG, ws + O_RWS, ws + O_RWY,
                                             ws + O_SG, ws + O_LP,
                                             out);
}